// Round 9
// baseline (48.337 us; speedup 1.0000x reference)
//
#include <hip/hip_runtime.h>

#define SQ3F 1.7320508075688772f
#define SQ5F 2.2360679774997896f
#define BLOCK 256
#define CHUNK 2048
#define ROUNDS 8        // CHUNK / BLOCK
#define EPB 1024        // edges per block = 4 * BLOCK

// m=2 basis matrices (exact transcription of _m2_basis; s = sqrt(3)/2)
__device__ const float M2B[5][3][3] = {
  {{0.f, 0.f, 0.8660254037844386f}, {0.f, 0.f, 0.f}, {0.8660254037844386f, 0.f, 0.f}},
  {{0.f, 0.8660254037844386f, 0.f}, {0.8660254037844386f, 0.f, 0.f}, {0.f, 0.f, 0.f}},
  {{-0.5f, 0.f, 0.f}, {0.f, 1.0f, 0.f}, {0.f, 0.f, -0.5f}},
  {{0.f, 0.f, 0.f}, {0.f, 0.f, 0.8660254037844386f}, {0.f, 0.8660254037844386f, 0.f}},
  {{-0.8660254037844386f, 0.f, 0.f}, {0.f, 0.f, 0.f}, {0.f, 0.f, 0.8660254037844386f}}
};

__device__ __forceinline__ void accum18(float* s, float nx, float ny,
                                        float ex, float ey, float ez) {
  float x2 = ex * ex, y2 = ey * ey, z2 = ez * ez;
  float s1x = SQ3F * ex, s1y = SQ3F * ey, s1z = SQ3F * ez;
  float s20 = SQ5F * SQ3F * ex * ez;
  float s21 = SQ5F * SQ3F * ex * ey;
  float s22 = SQ5F * (y2 - 0.5f * (x2 + z2));
  float s23 = SQ5F * SQ3F * ey * ez;
  float s24 = SQ5F * 0.5f * SQ3F * (z2 - x2);
  s[0] += nx;        s[1] += ny;
  s[2] += nx * s1x;  s[3] += nx * s1y;  s[4] += nx * s1z;
  s[5] += ny * s1x;  s[6] += ny * s1y;  s[7] += ny * s1z;
  s[8]  += nx * s20; s[9]  += nx * s21; s[10] += nx * s22;
  s[11] += nx * s23; s[12] += nx * s24;
  s[13] += ny * s20; s[14] += ny * s21; s[15] += ny * s22;
  s[16] += ny * s23; s[17] += ny * s24;
}

// block-wide reduce of 18 per-thread sums -> dst[0..18)
__device__ __forceinline__ void block_reduce_store(float* s, float* dst) {
  const int t = threadIdx.x, lane = t & 63, wave = t >> 6;
#pragma unroll
  for (int j = 0; j < 18; ++j)
    for (int o = 32; o; o >>= 1) s[j] += __shfl_down(s[j], o);
  __shared__ float ls[4][18];
  if (lane == 0) {
#pragma unroll
    for (int j = 0; j < 18; ++j) ls[wave][j] = s[j];
  }
  __syncthreads();
  if (t < 18) dst[t] = ls[0][t] + ls[1][t] + ls[2][t] + ls[3][t];
}

// full epilogue: accS (shared, 18 floats) -> out[5]; all 256 threads of one block
__device__ void do_finalize(const float* accS,
                            const float* w0, const float* w1, const float* w2,
                            const float* w_0e2e, const float* w_2e0e,
                            const float* w_1o1o, const float* w_2e2e,
                            float* out) {
  const int t = threadIdx.x;
  __shared__ float g0[64], g1[24][3], g2[16][5];
  __shared__ float a16[16], c16[16], T1[24][3], T2[16][5];
  __shared__ float A1[3][3], A2[5][5];
  __shared__ float W112s[45], W222s[125];
  __shared__ float rn112, rn222;
  if (t >= 64 && t < 109) W112s[t - 64] = 0.f;
  __syncthreads();   // accS + W112 zero visible

  const float inv = 0.28867513459481287f;  // 1/sqrt(12)
  if (t < 64) {
    g0[t] = inv * (accS[0] * w0[t] + accS[1] * w0[64 + t]);
  } else if (t < 136) {
    int i2 = t - 64, w = i2 / 3, j = i2 % 3;
    g1[w][j] = inv * (accS[2 + j] * w1[w] + accS[5 + j] * w1[24 + w]);
  } else if (t < 216) {
    int i2 = t - 136, w = i2 / 5, j = i2 % 5;
    g2[w][j] = inv * (accS[8 + j] * w2[w] + accS[13 + j] * w2[16 + w]);
  } else if (t < 241) {  // build W222 (25 threads)
    int idx = t - 216, i = idx / 5, j = idx % 5;
    float P[3][3];
    for (int a = 0; a < 3; ++a)
      for (int bb = 0; bb < 3; ++bb) {
        float sacc = 0.f;
        for (int cc = 0; cc < 3; ++cc)
          sacc += M2B[i][a][cc] * M2B[j][cc][bb] + M2B[j][a][cc] * M2B[i][cc][bb];
        P[a][bb] = 0.5f * sacc;
      }
    float tr3 = (P[0][0] + P[1][1] + P[2][2]) * (1.0f / 3.0f);
    P[0][0] -= tr3; P[1][1] -= tr3; P[2][2] -= tr3;
    for (int k = 0; k < 5; ++k) {
      float sacc = 0.f;
      for (int a = 0; a < 3; ++a)
        for (int bb = 0; bb < 3; ++bb) sacc += P[a][bb] * M2B[k][bb][a];
      W222s[(i * 5 + j) * 5 + k] = sacc * (1.0f / 1.5f);
    }
  }
  if (t == 0) {  // W112 nonzeros
    const float sq = 0.8660254037844386f;
    W112s[(0 * 3 + 2) * 5 + 0] = sq;  W112s[(2 * 3 + 0) * 5 + 0] = sq;
    W112s[(0 * 3 + 1) * 5 + 1] = sq;  W112s[(1 * 3 + 0) * 5 + 1] = sq;
    W112s[(1 * 3 + 1) * 5 + 2] = 1.0f;
    W112s[(0 * 3 + 0) * 5 + 2] = -0.5f;
    W112s[(2 * 3 + 2) * 5 + 2] = -0.5f;
    W112s[(1 * 3 + 2) * 5 + 3] = sq;  W112s[(2 * 3 + 1) * 5 + 3] = sq;
    W112s[(2 * 3 + 2) * 5 + 4] = sq;
    W112s[(0 * 3 + 0) * 5 + 4] = -sq;
  }
  __syncthreads();
  if (t == 0) { float ss = 0.f; for (int i = 0; i < 45; ++i)  ss += W112s[i] * W112s[i]; rn112 = rsqrtf(ss); }
  if (t == 1) { float ss = 0.f; for (int i = 0; i < 125; ++i) ss += W222s[i] * W222s[i]; rn222 = rsqrtf(ss); }
  __syncthreads();
  if (t < 45) W112s[t] *= rn112;
  else if (t < 170) W222s[t - 45] *= rn222;
  __syncthreads();

  if (t < 16) {
    float ssum = 0.f; for (int u = 0; u < 64; ++u) ssum += w_0e2e[u * 16 + t] * g0[u];
    a16[t] = ssum;
  } else if (t < 32) {
    int u = t - 16; float ssum = 0.f;
    for (int v = 0; v < 64; ++v) ssum += w_2e0e[u * 64 + v] * g0[v];
    c16[u] = ssum;
  } else if (t < 104) {
    int i2 = t - 32, u = i2 / 3, j = i2 % 3; float ssum = 0.f;
    for (int v = 0; v < 24; ++v) ssum += w_1o1o[u * 24 + v] * g1[v][j];
    T1[u][j] = ssum;
  } else if (t < 184) {
    int i2 = t - 104, u = i2 / 5, j = i2 % 5; float ssum = 0.f;
    for (int v = 0; v < 16; ++v) ssum += w_2e2e[u * 16 + v] * g2[v][j];
    T2[u][j] = ssum;
  }
  __syncthreads();
  if (t < 9) {
    int i = t / 3, j = t % 3; float ssum = 0.f;
    for (int u = 0; u < 24; ++u) ssum += g1[u][i] * T1[u][j];
    A1[i][j] = ssum;
  } else if (t < 34) {
    int i2 = t - 9, i = i2 / 5, j = i2 % 5; float ssum = 0.f;
    for (int u = 0; u < 16; ++u) ssum += g2[u][i] * T2[u][j];
    A2[i][j] = ssum;
  }
  __syncthreads();
  if (t < 5) {
    const float inv_s5 = 0.4472135954999579f;
    const float c = sqrtf(5.0f / 5248.0f);
    float s12 = 0.f;
    for (int v = 0; v < 16; ++v) s12 += (a16[v] + c16[v]) * g2[v][t];
    float s3 = 0.f;
    for (int i = 0; i < 3; ++i)
      for (int j = 0; j < 3; ++j) s3 += A1[i][j] * W112s[(i * 3 + j) * 5 + t];
    float s4 = 0.f;
    for (int i = 0; i < 5; ++i)
      for (int j = 0; j < 5; ++j) s4 += A2[i][j] * W222s[(i * 5 + j) * 5 + t];
    out[t] = c * (inv_s5 * s12 + s3 + s4);
  }
}

// ---- fused: canon check + speculative edges + ticket + finalize ----
__global__ void __launch_bounds__(BLOCK)
fused_kernel(const float2* __restrict__ x, const float* __restrict__ pos,
             int N, int E, int nchunks,
             int* __restrict__ tick,            // [33], zeroed by memset node
             int* __restrict__ counts, int* __restrict__ canon,
             unsigned short* __restrict__ slabF, unsigned short* __restrict__ slabT,
             float* __restrict__ partials,
             const float* __restrict__ w0, const float* __restrict__ w1,
             const float* __restrict__ w2, const float* __restrict__ w_0e2e,
             const float* __restrict__ w_2e0e, const float* __restrict__ w_1o1o,
             const float* __restrict__ w_2e2e, float* __restrict__ out) {
  const int b = blockIdx.x, t = threadIdx.x;
  const int lane = t & 63, wave = t >> 6;
  const int chunkBase = b * CHUNK;

  // ---- part A: canonical check of own chunk (float4 loads) ----
  int ok = 1;
  {
    const float4* x4 = (const float4*)x;       // one float4 = 2 elements
    const int base4 = b * (CHUNK / 2);
#pragma unroll
    for (int r = 0; r < ROUNDS / 2; ++r) {
      int i4 = base4 + r * BLOCK + t;
      int i0 = 2 * i4, i1 = i0 + 1;
      if (i1 < N) {
        float4 v = x4[i4];
        ok &= (int)((v.x > 0.5f) == (i0 < E)) & (int)((v.y > 0.5f) == (i0 >= E))
            & (int)((v.z > 0.5f) == (i1 < E)) & (int)((v.w > 0.5f) == (i1 >= E));
      } else if (i0 < N) {
        float2 v = x[i0];
        ok &= (int)((v.x > 0.5f) == (i0 < E)) & (int)((v.y > 0.5f) == (i0 >= E));
      }
    }
  }
  ok = __all(ok) ? 1 : 0;
  __shared__ int okW[4];
  if (lane == 0) okW[wave] = ok;
  __syncthreads();
  const int chunkCanon = okW[0] & okW[1] & okW[2] & okW[3];

  if (chunkCanon) {
    if (t == 0) {
      int hi = chunkBase + CHUNK; if (hi > N) hi = N;
      int span = hi - chunkBase; if (span < 0) span = 0;
      int lf = E - chunkBase; if (lf < 0) lf = 0; if (lf > span) lf = span;
      counts[2 * b] = lf; counts[2 * b + 1] = span - lf;
      canon[b] = 1;
    }
  } else {
    // non-canonical chunk: ballot compaction (x re-read is cache-hot)
    __shared__ int wc[2][4][2];
    unsigned short* sF = slabF + (size_t)b * CHUNK;
    unsigned short* sT = slabT + (size_t)b * CHUNK;
    int localF = 0, localT = 0;
    for (int r = 0; r < ROUNDS; ++r) {
      const int li = r * BLOCK + t;
      const int i = chunkBase + li;
      bool mf = false, mt = false;
      if (i < N) { float2 v = x[i]; mf = v.x > 0.5f; mt = v.y > 0.5f; }
      unsigned long long bf = __ballot(mf);
      unsigned long long bt = __ballot(mt);
      const int p = r & 1;
      if (lane == 0) { wc[p][wave][0] = __popcll(bf); wc[p][wave][1] = __popcll(bt); }
      __syncthreads();
      int woF = 0, woT = 0, rtF = 0, rtT = 0;
      for (int w = 0; w < 4; ++w) {
        int a = wc[p][w][0], c = wc[p][w][1];
        if (w < wave) { woF += a; woT += c; }
        rtF += a; rtT += c;
      }
      unsigned long long lm = (1ull << lane) - 1ull;
      if (mf) sF[localF + woF + (int)__popcll(bf & lm)] = (unsigned short)li;
      if (mt) sT[localT + woT + (int)__popcll(bt & lm)] = (unsigned short)li;
      localF += rtF; localT += rtT;
    }
    if (t == 0) {
      counts[2 * b] = localF; counts[2 * b + 1] = localT;
      canon[b] = 0;
    }
  }

  // ---- part B: speculative canonical edge slice ----
  float s[18];
#pragma unroll
  for (int j = 0; j < 18; ++j) s[j] = 0.f;
  const int k0 = b * EPB;
  if (k0 < E) {
    int k1 = k0 + EPB; if (k1 > E) k1 = E;
    if ((E & 3) == 0) {
      int k = k0 + 4 * t;
      if (k + 4 <= k1) {
        const int g = k >> 2;
        const float4* pF4 = (const float4*)pos;
        const float4* pT4 = (const float4*)(pos + 3 * (size_t)E);
        const float4* xT4 = (const float4*)((const float*)x + 2 * (size_t)E);
        float4 fa = pF4[3 * g], fb = pF4[3 * g + 1], fc = pF4[3 * g + 2];
        float4 ta = pT4[3 * g], tb = pT4[3 * g + 1], tc = pT4[3 * g + 2];
        float4 xa = xT4[2 * g], xb = xT4[2 * g + 1];
        accum18(s, xa.x, xa.y, ta.x - fa.x, ta.y - fa.y, ta.z - fa.z);
        accum18(s, xa.z, xa.w, ta.w - fa.w, tb.x - fb.x, tb.y - fb.y);
        accum18(s, xb.x, xb.y, tb.z - fb.z, tb.w - fb.w, tc.x - fc.x);
        accum18(s, xb.z, xb.w, tc.y - fc.y, tc.z - fc.z, tc.w - fc.w);
      } else {
        for (int kk = k; kk < k1; ++kk) {
          float2 nf = x[E + kk];
          accum18(s, nf.x, nf.y,
                  pos[3 * (size_t)(E + kk)]     - pos[3 * (size_t)kk],
                  pos[3 * (size_t)(E + kk) + 1] - pos[3 * (size_t)kk + 1],
                  pos[3 * (size_t)(E + kk) + 2] - pos[3 * (size_t)kk + 2]);
        }
      }
    } else {
      for (int k = k0 + t; k < k1; k += BLOCK) {
        float2 nf = x[E + k];
        accum18(s, nf.x, nf.y,
                pos[3 * (size_t)(E + k)]     - pos[3 * (size_t)k],
                pos[3 * (size_t)(E + k) + 1] - pos[3 * (size_t)k + 1],
                pos[3 * (size_t)(E + k) + 2] - pos[3 * (size_t)k + 2]);
      }
    }
  }
  __syncthreads();
  block_reduce_store(s, partials + (size_t)b * 18);
  __syncthreads();                 // partials row fully written (t<18)

  // ---- two-level ticket: last block finalizes ----
  __shared__ int winFlag;
  if (t == 0) {
    __threadfence();               // flush this block's stores (shared L2)
    const int nb = nchunks;
    const int j = b & 31;
    const int cntj = ((nb - 1 - j) >> 5) + 1;
    int w = 0;
    int o1 = atomicAdd(&tick[j], 1);
    if (o1 == cntj - 1) {
      __threadfence();
      const int nSub = nb < 32 ? nb : 32;
      int o2 = atomicAdd(&tick[32], 1);
      if (o2 == nSub - 1) w = 1;
    }
    winFlag = w;
  }
  __syncthreads();
  if (!winFlag) return;
  if (t == 0) __threadfence();     // acquire: see all blocks' stores
  __syncthreads();

  // ---- winner: all-canonical? ----
  __shared__ int cr[4];
  int myok = 1;
  for (int k = t; k < nchunks; k += BLOCK) myok &= canon[k];
  myok = __all(myok) ? 1 : 0;
  if (lane == 0) cr[wave] = myok;
  __syncthreads();
  const int allCanon = cr[0] & cr[1] & cr[2] & cr[3];
  __shared__ float accS[18];

  if (allCanon) {
    float s2[18];
#pragma unroll
    for (int j = 0; j < 18; ++j) s2[j] = 0.f;
    for (int p = t; p < nchunks; p += BLOCK) {
#pragma unroll
      for (int j = 0; j < 18; ++j) s2[j] += partials[(size_t)p * 18 + j];
    }
    __syncthreads();
    block_reduce_store(s2, accS);
    do_finalize(accS, w0, w1, w2, w_0e2e, w_2e0e, w_1o1o, w_2e2e, out);
    return;
  }

  // ---- generic fallback: this single block computes everything exactly ----
  __shared__ int pf[1025], pt[1025];
  __shared__ char cs[1024];
  for (int k = t; k < 1024; k += BLOCK) {
    pf[k] = (k < nchunks) ? counts[2 * k]     : 0;
    pt[k] = (k < nchunks) ? counts[2 * k + 1] : 0;
    cs[k] = (k < nchunks) ? (char)canon[k]    : (char)1;
  }
  __syncthreads();
  int a0 = pf[4 * t], a1 = pf[4 * t + 1], a2 = pf[4 * t + 2], a3 = pf[4 * t + 3];
  int b0 = pt[4 * t], b1 = pt[4 * t + 1], b2 = pt[4 * t + 2], b3 = pt[4 * t + 3];
  int sA = a0 + a1 + a2 + a3, sB = b0 + b1 + b2 + b3;
  int vA = sA, vB = sB;
  for (int o = 1; o < 64; o <<= 1) {
    int uA = __shfl_up(vA, o), uB = __shfl_up(vB, o);
    if (lane >= o) { vA += uA; vB += uB; }
  }
  __shared__ int wtA[4], wtB[4];
  if (lane == 63) { wtA[wave] = vA; wtB[wave] = vB; }
  __syncthreads();
  int woA = 0, woB = 0;
  for (int w = 0; w < wave; ++w) { woA += wtA[w]; woB += wtB[w]; }
  const int exA = vA - sA + woA;
  const int exB = vB - sB + woB;
  __syncthreads();
  pf[4 * t] = exA; pf[4 * t + 1] = exA + a0; pf[4 * t + 2] = exA + a0 + a1; pf[4 * t + 3] = exA + a0 + a1 + a2;
  pt[4 * t] = exB; pt[4 * t + 1] = exB + b0; pt[4 * t + 2] = exB + b0 + b1; pt[4 * t + 3] = exB + b0 + b1 + b2;
  if (t == BLOCK - 1) { pf[1024] = exA + sA; pt[1024] = exB + sB; }
  __syncthreads();

  int cF = pf[nchunks]; if (cF > E) cF = E;
  int cT = pt[nchunks]; if (cT > E) cT = E;

  float s2[18];
#pragma unroll
  for (int j = 0; j < 18; ++j) s2[j] = 0.f;
  for (int k = t; k < E; k += BLOCK) {
    int idxF = 0, idxT = 0;                       // nonzero pad fill_value = 0
    if (k < cF) {
      int lo = 0, hi = nchunks - 1;
      while (lo < hi) { int mid = (lo + hi) >> 1; if (pf[mid + 1] <= k) lo = mid + 1; else hi = mid; }
      int loc = k - pf[lo];
      idxF = lo * CHUNK + (cs[lo] ? loc : (int)slabF[(size_t)lo * CHUNK + loc]);
    }
    if (k < cT) {
      int lo = 0, hi = nchunks - 1;
      while (lo < hi) { int mid = (lo + hi) >> 1; if (pt[mid + 1] <= k) lo = mid + 1; else hi = mid; }
      int loc = k - pt[lo];
      int startT = pf[lo + 1] - pf[lo];           // canon chunk: to-elems follow from-elems
      idxT = lo * CHUNK + (cs[lo] ? (startT + loc) : (int)slabT[(size_t)lo * CHUNK + loc]);
    }
    float2 nf = x[idxT];
    float ex = pos[3 * (size_t)idxT]     - pos[3 * (size_t)idxF];
    float ey = pos[3 * (size_t)idxT + 1] - pos[3 * (size_t)idxF + 1];
    float ez = pos[3 * (size_t)idxT + 2] - pos[3 * (size_t)idxF + 2];
    accum18(s2, nf.x, nf.y, ex, ey, ez);
  }
  __syncthreads();
  block_reduce_store(s2, accS);
  do_finalize(accS, w0, w1, w2, w_0e2e, w_2e0e, w_1o1o, w_2e2e, out);
}

extern "C" void kernel_launch(void* const* d_in, const int* in_sizes, int n_in,
                              void* d_out, int out_size, void* d_ws, size_t ws_size,
                              hipStream_t stream) {
  const float2* x      = (const float2*)d_in[0];
  const float*  pos    = (const float*)d_in[1];
  const float*  tp1_w0 = (const float*)d_in[2];
  const float*  tp1_w1 = (const float*)d_in[3];
  const float*  tp1_w2 = (const float*)d_in[4];
  const float*  w_0e2e = (const float*)d_in[5];
  const float*  w_2e0e = (const float*)d_in[6];
  const float*  w_1o1o = (const float*)d_in[7];
  const float*  w_2e2e = (const float*)d_in[8];
  float* outp = (float*)d_out;

  const int N = in_sizes[0] / 2;
  const int E = N / 2;
  const int nchunks = (N + CHUNK - 1) / CHUNK;   // 977 for N=2e6 (must be <=1024)

  // ws layout: tick 256B | counts 8KB | canon 4KB | partials 72KB | slabF | slabT
  char* ws = (char*)d_ws;
  int*   tick     = (int*)ws;
  int*   counts   = (int*)(ws + 256);
  int*   canon    = (int*)(ws + 256 + 8192);
  float* partials = (float*)(ws + 256 + 8192 + 4096);
  unsigned short* slabF = (unsigned short*)(ws + 256 + 8192 + 4096 + 73728);
  unsigned short* slabT = slabF + (size_t)nchunks * CHUNK;

  hipMemsetAsync(tick, 0, 33 * sizeof(int), stream);
  fused_kernel<<<nchunks, BLOCK, 0, stream>>>(x, pos, N, E, nchunks, tick,
                                              counts, canon, slabF, slabT, partials,
                                              tp1_w0, tp1_w1, tp1_w2,
                                              w_0e2e, w_2e0e, w_1o1o, w_2e2e, outp);
}

// Round 10
// 46.470 us; speedup vs baseline: 1.0402x; 1.0402x over previous
//
#include <hip/hip_runtime.h>

#define SQ3F 1.7320508075688772f
#define SQ5F 2.2360679774997896f
#define BLOCK 256
#define CHUNK 2048
#define ROUNDS 8        // CHUNK / BLOCK
#define EPB 1024        // edges per block = 4 * BLOCK
#define TPAD 32         // ints per ticket slot (128 B line) — avoid same-line atomic serialization

// m=2 basis matrices (exact transcription of _m2_basis; s = sqrt(3)/2)
__device__ const float M2B[5][3][3] = {
  {{0.f, 0.f, 0.8660254037844386f}, {0.f, 0.f, 0.f}, {0.8660254037844386f, 0.f, 0.f}},
  {{0.f, 0.8660254037844386f, 0.f}, {0.8660254037844386f, 0.f, 0.f}, {0.f, 0.f, 0.f}},
  {{-0.5f, 0.f, 0.f}, {0.f, 1.0f, 0.f}, {0.f, 0.f, -0.5f}},
  {{0.f, 0.f, 0.f}, {0.f, 0.f, 0.8660254037844386f}, {0.f, 0.8660254037844386f, 0.f}},
  {{-0.8660254037844386f, 0.f, 0.f}, {0.f, 0.f, 0.f}, {0.f, 0.f, 0.8660254037844386f}}
};

__device__ __forceinline__ void accum18(float* s, float nx, float ny,
                                        float ex, float ey, float ez) {
  float x2 = ex * ex, y2 = ey * ey, z2 = ez * ez;
  float s1x = SQ3F * ex, s1y = SQ3F * ey, s1z = SQ3F * ez;
  float s20 = SQ5F * SQ3F * ex * ez;
  float s21 = SQ5F * SQ3F * ex * ey;
  float s22 = SQ5F * (y2 - 0.5f * (x2 + z2));
  float s23 = SQ5F * SQ3F * ey * ez;
  float s24 = SQ5F * 0.5f * SQ3F * (z2 - x2);
  s[0] += nx;        s[1] += ny;
  s[2] += nx * s1x;  s[3] += nx * s1y;  s[4] += nx * s1z;
  s[5] += ny * s1x;  s[6] += ny * s1y;  s[7] += ny * s1z;
  s[8]  += nx * s20; s[9]  += nx * s21; s[10] += nx * s22;
  s[11] += nx * s23; s[12] += nx * s24;
  s[13] += ny * s20; s[14] += ny * s21; s[15] += ny * s22;
  s[16] += ny * s23; s[17] += ny * s24;
}

// block-wide reduce of 18 per-thread sums -> dst[0..18)
__device__ __forceinline__ void block_reduce_store(float* s, float* dst) {
  const int t = threadIdx.x, lane = t & 63, wave = t >> 6;
#pragma unroll
  for (int j = 0; j < 18; ++j)
    for (int o = 32; o; o >>= 1) s[j] += __shfl_down(s[j], o);
  __shared__ float ls[4][18];
  if (lane == 0) {
#pragma unroll
    for (int j = 0; j < 18; ++j) ls[wave][j] = s[j];
  }
  __syncthreads();
  if (t < 18) dst[t] = ls[0][t] + ls[1][t] + ls[2][t] + ls[3][t];
}

// full epilogue: accS (shared, 18 floats) -> out[5]; all 256 threads of one block
__device__ void do_finalize(const float* accS,
                            const float* w0, const float* w1, const float* w2,
                            const float* w_0e2e, const float* w_2e0e,
                            const float* w_1o1o, const float* w_2e2e,
                            float* out) {
  const int t = threadIdx.x;
  __shared__ float g0[64], g1[24][3], g2[16][5];
  __shared__ float a16[16], c16[16], T1[24][3], T2[16][5];
  __shared__ float A1[3][3], A2[5][5];
  __shared__ float W112s[45], W222s[125];
  __shared__ float rn112, rn222;
  if (t >= 64 && t < 109) W112s[t - 64] = 0.f;
  __syncthreads();   // accS + W112 zero visible

  const float inv = 0.28867513459481287f;  // 1/sqrt(12)
  if (t < 64) {
    g0[t] = inv * (accS[0] * w0[t] + accS[1] * w0[64 + t]);
  } else if (t < 136) {
    int i2 = t - 64, w = i2 / 3, j = i2 % 3;
    g1[w][j] = inv * (accS[2 + j] * w1[w] + accS[5 + j] * w1[24 + w]);
  } else if (t < 216) {
    int i2 = t - 136, w = i2 / 5, j = i2 % 5;
    g2[w][j] = inv * (accS[8 + j] * w2[w] + accS[13 + j] * w2[16 + w]);
  } else if (t < 241) {  // build W222 (25 threads)
    int idx = t - 216, i = idx / 5, j = idx % 5;
    float P[3][3];
    for (int a = 0; a < 3; ++a)
      for (int bb = 0; bb < 3; ++bb) {
        float sacc = 0.f;
        for (int cc = 0; cc < 3; ++cc)
          sacc += M2B[i][a][cc] * M2B[j][cc][bb] + M2B[j][a][cc] * M2B[i][cc][bb];
        P[a][bb] = 0.5f * sacc;
      }
    float tr3 = (P[0][0] + P[1][1] + P[2][2]) * (1.0f / 3.0f);
    P[0][0] -= tr3; P[1][1] -= tr3; P[2][2] -= tr3;
    for (int k = 0; k < 5; ++k) {
      float sacc = 0.f;
      for (int a = 0; a < 3; ++a)
        for (int bb = 0; bb < 3; ++bb) sacc += P[a][bb] * M2B[k][bb][a];
      W222s[(i * 5 + j) * 5 + k] = sacc * (1.0f / 1.5f);
    }
  }
  if (t == 0) {  // W112 nonzeros
    const float sq = 0.8660254037844386f;
    W112s[(0 * 3 + 2) * 5 + 0] = sq;  W112s[(2 * 3 + 0) * 5 + 0] = sq;
    W112s[(0 * 3 + 1) * 5 + 1] = sq;  W112s[(1 * 3 + 0) * 5 + 1] = sq;
    W112s[(1 * 3 + 1) * 5 + 2] = 1.0f;
    W112s[(0 * 3 + 0) * 5 + 2] = -0.5f;
    W112s[(2 * 3 + 2) * 5 + 2] = -0.5f;
    W112s[(1 * 3 + 2) * 5 + 3] = sq;  W112s[(2 * 3 + 1) * 5 + 3] = sq;
    W112s[(2 * 3 + 2) * 5 + 4] = sq;
    W112s[(0 * 3 + 0) * 5 + 4] = -sq;
  }
  __syncthreads();
  if (t == 0) { float ss = 0.f; for (int i = 0; i < 45; ++i)  ss += W112s[i] * W112s[i]; rn112 = rsqrtf(ss); }
  if (t == 1) { float ss = 0.f; for (int i = 0; i < 125; ++i) ss += W222s[i] * W222s[i]; rn222 = rsqrtf(ss); }
  __syncthreads();
  if (t < 45) W112s[t] *= rn112;
  else if (t < 170) W222s[t - 45] *= rn222;
  __syncthreads();

  if (t < 16) {
    float ssum = 0.f; for (int u = 0; u < 64; ++u) ssum += w_0e2e[u * 16 + t] * g0[u];
    a16[t] = ssum;
  } else if (t < 32) {
    int u = t - 16; float ssum = 0.f;
    for (int v = 0; v < 64; ++v) ssum += w_2e0e[u * 64 + v] * g0[v];
    c16[u] = ssum;
  } else if (t < 104) {
    int i2 = t - 32, u = i2 / 3, j = i2 % 3; float ssum = 0.f;
    for (int v = 0; v < 24; ++v) ssum += w_1o1o[u * 24 + v] * g1[v][j];
    T1[u][j] = ssum;
  } else if (t < 184) {
    int i2 = t - 104, u = i2 / 5, j = i2 % 5; float ssum = 0.f;
    for (int v = 0; v < 16; ++v) ssum += w_2e2e[u * 16 + v] * g2[v][j];
    T2[u][j] = ssum;
  }
  __syncthreads();
  if (t < 9) {
    int i = t / 3, j = t % 3; float ssum = 0.f;
    for (int u = 0; u < 24; ++u) ssum += g1[u][i] * T1[u][j];
    A1[i][j] = ssum;
  } else if (t < 34) {
    int i2 = t - 9, i = i2 / 5, j = i2 % 5; float ssum = 0.f;
    for (int u = 0; u < 16; ++u) ssum += g2[u][i] * T2[u][j];
    A2[i][j] = ssum;
  }
  __syncthreads();
  if (t < 5) {
    const float inv_s5 = 0.4472135954999579f;
    const float c = sqrtf(5.0f / 5248.0f);
    float s12 = 0.f;
    for (int v = 0; v < 16; ++v) s12 += (a16[v] + c16[v]) * g2[v][t];
    float s3 = 0.f;
    for (int i = 0; i < 3; ++i)
      for (int j = 0; j < 3; ++j) s3 += A1[i][j] * W112s[(i * 3 + j) * 5 + t];
    float s4 = 0.f;
    for (int i = 0; i < 5; ++i)
      for (int j = 0; j < 5; ++j) s4 += A2[i][j] * W222s[(i * 5 + j) * 5 + t];
    out[t] = c * (inv_s5 * s12 + s3 + s4);
  }
}

// ---- fused: canon check + speculative edges + padded ticket + finalize ----
__global__ void __launch_bounds__(BLOCK)
fused_kernel(const float2* __restrict__ x, const float* __restrict__ pos,
             int N, int E, int nchunks,
             int* __restrict__ tick,            // [33*TPAD], zeroed by memset node
             int* __restrict__ counts, int* __restrict__ canon,
             unsigned short* __restrict__ slabF, unsigned short* __restrict__ slabT,
             float* __restrict__ partials,
             const float* __restrict__ w0, const float* __restrict__ w1,
             const float* __restrict__ w2, const float* __restrict__ w_0e2e,
             const float* __restrict__ w_2e0e, const float* __restrict__ w_1o1o,
             const float* __restrict__ w_2e2e, float* __restrict__ out) {
  const int b = blockIdx.x, t = threadIdx.x;
  const int lane = t & 63, wave = t >> 6;
  const int chunkBase = b * CHUNK;

  // ---- part A: canonical check of own chunk (float4 loads) ----
  int ok = 1;
  {
    const float4* x4 = (const float4*)x;       // one float4 = 2 elements
    const int base4 = b * (CHUNK / 2);
#pragma unroll
    for (int r = 0; r < ROUNDS / 2; ++r) {
      int i4 = base4 + r * BLOCK + t;
      int i0 = 2 * i4, i1 = i0 + 1;
      if (i1 < N) {
        float4 v = x4[i4];
        ok &= (int)((v.x > 0.5f) == (i0 < E)) & (int)((v.y > 0.5f) == (i0 >= E))
            & (int)((v.z > 0.5f) == (i1 < E)) & (int)((v.w > 0.5f) == (i1 >= E));
      } else if (i0 < N) {
        float2 v = x[i0];
        ok &= (int)((v.x > 0.5f) == (i0 < E)) & (int)((v.y > 0.5f) == (i0 >= E));
      }
    }
  }
  ok = __all(ok) ? 1 : 0;
  __shared__ int okW[4];
  if (lane == 0) okW[wave] = ok;
  __syncthreads();
  const int chunkCanon = okW[0] & okW[1] & okW[2] & okW[3];

  if (chunkCanon) {
    if (t == 0) {
      int hi = chunkBase + CHUNK; if (hi > N) hi = N;
      int span = hi - chunkBase; if (span < 0) span = 0;
      int lf = E - chunkBase; if (lf < 0) lf = 0; if (lf > span) lf = span;
      counts[2 * b] = lf; counts[2 * b + 1] = span - lf;
      canon[b] = 1;
    }
  } else {
    // non-canonical chunk: ballot compaction (x re-read is cache-hot)
    __shared__ int wc[2][4][2];
    unsigned short* sF = slabF + (size_t)b * CHUNK;
    unsigned short* sT = slabT + (size_t)b * CHUNK;
    int localF = 0, localT = 0;
    for (int r = 0; r < ROUNDS; ++r) {
      const int li = r * BLOCK + t;
      const int i = chunkBase + li;
      bool mf = false, mt = false;
      if (i < N) { float2 v = x[i]; mf = v.x > 0.5f; mt = v.y > 0.5f; }
      unsigned long long bf = __ballot(mf);
      unsigned long long bt = __ballot(mt);
      const int p = r & 1;
      if (lane == 0) { wc[p][wave][0] = __popcll(bf); wc[p][wave][1] = __popcll(bt); }
      __syncthreads();
      int woF = 0, woT = 0, rtF = 0, rtT = 0;
      for (int w = 0; w < 4; ++w) {
        int a = wc[p][w][0], c = wc[p][w][1];
        if (w < wave) { woF += a; woT += c; }
        rtF += a; rtT += c;
      }
      unsigned long long lm = (1ull << lane) - 1ull;
      if (mf) sF[localF + woF + (int)__popcll(bf & lm)] = (unsigned short)li;
      if (mt) sT[localT + woT + (int)__popcll(bt & lm)] = (unsigned short)li;
      localF += rtF; localT += rtT;
    }
    if (t == 0) {
      counts[2 * b] = localF; counts[2 * b + 1] = localT;
      canon[b] = 0;
    }
  }

  // ---- part B: speculative canonical edge slice ----
  float s[18];
#pragma unroll
  for (int j = 0; j < 18; ++j) s[j] = 0.f;
  const int k0 = b * EPB;
  if (k0 < E) {
    int k1 = k0 + EPB; if (k1 > E) k1 = E;
    if ((E & 3) == 0) {
      int k = k0 + 4 * t;
      if (k + 4 <= k1) {
        const int g = k >> 2;
        const float4* pF4 = (const float4*)pos;
        const float4* pT4 = (const float4*)(pos + 3 * (size_t)E);
        const float4* xT4 = (const float4*)((const float*)x + 2 * (size_t)E);
        float4 fa = pF4[3 * g], fb = pF4[3 * g + 1], fc = pF4[3 * g + 2];
        float4 ta = pT4[3 * g], tb = pT4[3 * g + 1], tc = pT4[3 * g + 2];
        float4 xa = xT4[2 * g], xb = xT4[2 * g + 1];
        accum18(s, xa.x, xa.y, ta.x - fa.x, ta.y - fa.y, ta.z - fa.z);
        accum18(s, xa.z, xa.w, ta.w - fa.w, tb.x - fb.x, tb.y - fb.y);
        accum18(s, xb.x, xb.y, tb.z - fb.z, tb.w - fb.w, tc.x - fc.x);
        accum18(s, xb.z, xb.w, tc.y - fc.y, tc.z - fc.z, tc.w - fc.w);
      } else {
        for (int kk = k; kk < k1; ++kk) {
          float2 nf = x[E + kk];
          accum18(s, nf.x, nf.y,
                  pos[3 * (size_t)(E + kk)]     - pos[3 * (size_t)kk],
                  pos[3 * (size_t)(E + kk) + 1] - pos[3 * (size_t)kk + 1],
                  pos[3 * (size_t)(E + kk) + 2] - pos[3 * (size_t)kk + 2]);
        }
      }
    } else {
      for (int k = k0 + t; k < k1; k += BLOCK) {
        float2 nf = x[E + k];
        accum18(s, nf.x, nf.y,
                pos[3 * (size_t)(E + k)]     - pos[3 * (size_t)k],
                pos[3 * (size_t)(E + k) + 1] - pos[3 * (size_t)k + 1],
                pos[3 * (size_t)(E + k) + 2] - pos[3 * (size_t)k + 2]);
      }
    }
  }
  __syncthreads();
  block_reduce_store(s, partials + (size_t)b * 18);
  __syncthreads();                 // partials row fully written (t<18)

  // ---- two-level ticket, one 128-B line per slot: last block finalizes ----
  __shared__ int winFlag;
  if (t == 0) {
    __threadfence();               // release this block's stores
    const int nb = nchunks;
    const int j = b & 31;
    const int cntj = ((nb - 1 - j) >> 5) + 1;
    int w = 0;
    int o1 = atomicAdd(&tick[j * TPAD], 1);
    if (o1 == cntj - 1) {
      __threadfence();
      const int nSub = nb < 32 ? nb : 32;
      int o2 = atomicAdd(&tick[32 * TPAD], 1);
      if (o2 == nSub - 1) w = 1;
    }
    winFlag = w;
  }
  __syncthreads();
  if (!winFlag) return;
  if (t == 0) __threadfence();     // acquire: see all blocks' stores
  __syncthreads();

  // ---- winner: all-canonical? ----
  __shared__ int cr[4];
  int myok = 1;
  for (int k = t; k < nchunks; k += BLOCK) myok &= canon[k];
  myok = __all(myok) ? 1 : 0;
  if (lane == 0) cr[wave] = myok;
  __syncthreads();
  const int allCanon = cr[0] & cr[1] & cr[2] & cr[3];
  __shared__ float accS[18];

  if (allCanon) {
    float s2[18];
#pragma unroll
    for (int j = 0; j < 18; ++j) s2[j] = 0.f;
    for (int p = t; p < nchunks; p += BLOCK) {
#pragma unroll
      for (int j = 0; j < 18; ++j) s2[j] += partials[(size_t)p * 18 + j];
    }
    __syncthreads();
    block_reduce_store(s2, accS);
    do_finalize(accS, w0, w1, w2, w_0e2e, w_2e0e, w_1o1o, w_2e2e, out);
    return;
  }

  // ---- generic fallback: this single block computes everything exactly ----
  __shared__ int pf[1025], pt[1025];
  __shared__ char cs[1024];
  for (int k = t; k < 1024; k += BLOCK) {
    pf[k] = (k < nchunks) ? counts[2 * k]     : 0;
    pt[k] = (k < nchunks) ? counts[2 * k + 1] : 0;
    cs[k] = (k < nchunks) ? (char)canon[k]    : (char)1;
  }
  __syncthreads();
  int a0 = pf[4 * t], a1 = pf[4 * t + 1], a2 = pf[4 * t + 2], a3 = pf[4 * t + 3];
  int b0 = pt[4 * t], b1 = pt[4 * t + 1], b2 = pt[4 * t + 2], b3 = pt[4 * t + 3];
  int sA = a0 + a1 + a2 + a3, sB = b0 + b1 + b2 + b3;
  int vA = sA, vB = sB;
  for (int o = 1; o < 64; o <<= 1) {
    int uA = __shfl_up(vA, o), uB = __shfl_up(vB, o);
    if (lane >= o) { vA += uA; vB += uB; }
  }
  __shared__ int wtA[4], wtB[4];
  if (lane == 63) { wtA[wave] = vA; wtB[wave] = vB; }
  __syncthreads();
  int woA = 0, woB = 0;
  for (int w = 0; w < wave; ++w) { woA += wtA[w]; woB += wtB[w]; }
  const int exA = vA - sA + woA;
  const int exB = vB - sB + woB;
  __syncthreads();
  pf[4 * t] = exA; pf[4 * t + 1] = exA + a0; pf[4 * t + 2] = exA + a0 + a1; pf[4 * t + 3] = exA + a0 + a1 + a2;
  pt[4 * t] = exB; pt[4 * t + 1] = exB + b0; pt[4 * t + 2] = exB + b0 + b1; pt[4 * t + 3] = exB + b0 + b1 + b2;
  if (t == BLOCK - 1) { pf[1024] = exA + sA; pt[1024] = exB + sB; }
  __syncthreads();

  int cF = pf[nchunks]; if (cF > E) cF = E;
  int cT = pt[nchunks]; if (cT > E) cT = E;

  float s2[18];
#pragma unroll
  for (int j = 0; j < 18; ++j) s2[j] = 0.f;
  for (int k = t; k < E; k += BLOCK) {
    int idxF = 0, idxT = 0;                       // nonzero pad fill_value = 0
    if (k < cF) {
      int lo = 0, hi = nchunks - 1;
      while (lo < hi) { int mid = (lo + hi) >> 1; if (pf[mid + 1] <= k) lo = mid + 1; else hi = mid; }
      int loc = k - pf[lo];
      idxF = lo * CHUNK + (cs[lo] ? loc : (int)slabF[(size_t)lo * CHUNK + loc]);
    }
    if (k < cT) {
      int lo = 0, hi = nchunks - 1;
      while (lo < hi) { int mid = (lo + hi) >> 1; if (pt[mid + 1] <= k) lo = mid + 1; else hi = mid; }
      int loc = k - pt[lo];
      int startT = pf[lo + 1] - pf[lo];           // canon chunk: to-elems follow from-elems
      idxT = lo * CHUNK + (cs[lo] ? (startT + loc) : (int)slabT[(size_t)lo * CHUNK + loc]);
    }
    float2 nf = x[idxT];
    float ex = pos[3 * (size_t)idxT]     - pos[3 * (size_t)idxF];
    float ey = pos[3 * (size_t)idxT + 1] - pos[3 * (size_t)idxF + 1];
    float ez = pos[3 * (size_t)idxT + 2] - pos[3 * (size_t)idxF + 2];
    accum18(s2, nf.x, nf.y, ex, ey, ez);
  }
  __syncthreads();
  block_reduce_store(s2, accS);
  do_finalize(accS, w0, w1, w2, w_0e2e, w_2e0e, w_1o1o, w_2e2e, out);
}

extern "C" void kernel_launch(void* const* d_in, const int* in_sizes, int n_in,
                              void* d_out, int out_size, void* d_ws, size_t ws_size,
                              hipStream_t stream) {
  const float2* x      = (const float2*)d_in[0];
  const float*  pos    = (const float*)d_in[1];
  const float*  tp1_w0 = (const float*)d_in[2];
  const float*  tp1_w1 = (const float*)d_in[3];
  const float*  tp1_w2 = (const float*)d_in[4];
  const float*  w_0e2e = (const float*)d_in[5];
  const float*  w_2e0e = (const float*)d_in[6];
  const float*  w_1o1o = (const float*)d_in[7];
  const float*  w_2e2e = (const float*)d_in[8];
  float* outp = (float*)d_out;

  const int N = in_sizes[0] / 2;
  const int E = N / 2;
  const int nchunks = (N + CHUNK - 1) / CHUNK;   // 977 for N=2e6 (must be <=1024)

  // ws layout: tick 33*128B (pad 8KB) | counts 8KB | canon 4KB | partials 72KB | slabF | slabT
  char* ws = (char*)d_ws;
  int*   tick     = (int*)ws;
  int*   counts   = (int*)(ws + 8192);
  int*   canon    = (int*)(ws + 8192 + 8192);
  float* partials = (float*)(ws + 8192 + 8192 + 4096);
  unsigned short* slabF = (unsigned short*)(ws + 8192 + 8192 + 4096 + 73728);
  unsigned short* slabT = slabF + (size_t)nchunks * CHUNK;

  hipMemsetAsync(tick, 0, 33 * TPAD * sizeof(int), stream);
  fused_kernel<<<nchunks, BLOCK, 0, stream>>>(x, pos, N, E, nchunks, tick,
                                              counts, canon, slabF, slabT, partials,
                                              tp1_w0, tp1_w1, tp1_w2,
                                              w_0e2e, w_2e0e, w_1o1o, w_2e2e, outp);
}

// Round 11
// 24.249 us; speedup vs baseline: 1.9933x; 1.9163x over previous
//
#include <hip/hip_runtime.h>

#define SQ3F 1.7320508075688772f
#define SQ5F 2.2360679774997896f
#define BLOCK 256
#define EPB 1024        // edges (and from-rows) per K1 block

// m=2 basis matrices (exact transcription of _m2_basis; s = sqrt(3)/2)
__device__ const float M2B[5][3][3] = {
  {{0.f, 0.f, 0.8660254037844386f}, {0.f, 0.f, 0.f}, {0.8660254037844386f, 0.f, 0.f}},
  {{0.f, 0.8660254037844386f, 0.f}, {0.8660254037844386f, 0.f, 0.f}, {0.f, 0.f, 0.f}},
  {{-0.5f, 0.f, 0.f}, {0.f, 1.0f, 0.f}, {0.f, 0.f, -0.5f}},
  {{0.f, 0.f, 0.f}, {0.f, 0.f, 0.8660254037844386f}, {0.f, 0.8660254037844386f, 0.f}},
  {{-0.8660254037844386f, 0.f, 0.f}, {0.f, 0.f, 0.f}, {0.f, 0.f, 0.8660254037844386f}}
};

__device__ __forceinline__ void accum18(float* s, float nx, float ny,
                                        float ex, float ey, float ez) {
  float x2 = ex * ex, y2 = ey * ey, z2 = ez * ez;
  float s1x = SQ3F * ex, s1y = SQ3F * ey, s1z = SQ3F * ez;
  float s20 = SQ5F * SQ3F * ex * ez;
  float s21 = SQ5F * SQ3F * ex * ey;
  float s22 = SQ5F * (y2 - 0.5f * (x2 + z2));
  float s23 = SQ5F * SQ3F * ey * ez;
  float s24 = SQ5F * 0.5f * SQ3F * (z2 - x2);
  s[0] += nx;        s[1] += ny;
  s[2] += nx * s1x;  s[3] += nx * s1y;  s[4] += nx * s1z;
  s[5] += ny * s1x;  s[6] += ny * s1y;  s[7] += ny * s1z;
  s[8]  += nx * s20; s[9]  += nx * s21; s[10] += nx * s22;
  s[11] += nx * s23; s[12] += nx * s24;
  s[13] += ny * s20; s[14] += ny * s21; s[15] += ny * s22;
  s[16] += ny * s23; s[17] += ny * s24;
}

// block-wide reduce of 18 per-thread sums -> dst[0..18)
__device__ __forceinline__ void block_reduce_store(float* s, float* dst) {
  const int t = threadIdx.x, lane = t & 63, wave = t >> 6;
#pragma unroll
  for (int j = 0; j < 18; ++j)
    for (int o = 32; o; o >>= 1) s[j] += __shfl_down(s[j], o);
  __shared__ float ls[4][18];
  if (lane == 0) {
#pragma unroll
    for (int j = 0; j < 18; ++j) ls[wave][j] = s[j];
  }
  __syncthreads();
  if (t < 18) dst[t] = ls[0][t] + ls[1][t] + ls[2][t] + ls[3][t];
}

// full epilogue: accS (shared, 18 floats) -> out[5]; all 256 threads of one block
__device__ void do_finalize(const float* accS,
                            const float* w0, const float* w1, const float* w2,
                            const float* w_0e2e, const float* w_2e0e,
                            const float* w_1o1o, const float* w_2e2e,
                            float* out) {
  const int t = threadIdx.x;
  __shared__ float g0[64], g1[24][3], g2[16][5];
  __shared__ float a16[16], c16[16], T1[24][3], T2[16][5];
  __shared__ float A1[3][3], A2[5][5];
  __shared__ float W112s[45], W222s[125];
  __shared__ float rn112, rn222;
  if (t >= 64 && t < 109) W112s[t - 64] = 0.f;
  __syncthreads();   // accS + W112 zero visible

  const float inv = 0.28867513459481287f;  // 1/sqrt(12)
  if (t < 64) {
    g0[t] = inv * (accS[0] * w0[t] + accS[1] * w0[64 + t]);
  } else if (t < 136) {
    int i2 = t - 64, w = i2 / 3, j = i2 % 3;
    g1[w][j] = inv * (accS[2 + j] * w1[w] + accS[5 + j] * w1[24 + w]);
  } else if (t < 216) {
    int i2 = t - 136, w = i2 / 5, j = i2 % 5;
    g2[w][j] = inv * (accS[8 + j] * w2[w] + accS[13 + j] * w2[16 + w]);
  } else if (t < 241) {  // build W222 (25 threads)
    int idx = t - 216, i = idx / 5, j = idx % 5;
    float P[3][3];
    for (int a = 0; a < 3; ++a)
      for (int bb = 0; bb < 3; ++bb) {
        float sacc = 0.f;
        for (int cc = 0; cc < 3; ++cc)
          sacc += M2B[i][a][cc] * M2B[j][cc][bb] + M2B[j][a][cc] * M2B[i][cc][bb];
        P[a][bb] = 0.5f * sacc;
      }
    float tr3 = (P[0][0] + P[1][1] + P[2][2]) * (1.0f / 3.0f);
    P[0][0] -= tr3; P[1][1] -= tr3; P[2][2] -= tr3;
    for (int k = 0; k < 5; ++k) {
      float sacc = 0.f;
      for (int a = 0; a < 3; ++a)
        for (int bb = 0; bb < 3; ++bb) sacc += P[a][bb] * M2B[k][bb][a];
      W222s[(i * 5 + j) * 5 + k] = sacc * (1.0f / 1.5f);
    }
  }
  if (t == 0) {  // W112 nonzeros
    const float sq = 0.8660254037844386f;
    W112s[(0 * 3 + 2) * 5 + 0] = sq;  W112s[(2 * 3 + 0) * 5 + 0] = sq;
    W112s[(0 * 3 + 1) * 5 + 1] = sq;  W112s[(1 * 3 + 0) * 5 + 1] = sq;
    W112s[(1 * 3 + 1) * 5 + 2] = 1.0f;
    W112s[(0 * 3 + 0) * 5 + 2] = -0.5f;
    W112s[(2 * 3 + 2) * 5 + 2] = -0.5f;
    W112s[(1 * 3 + 2) * 5 + 3] = sq;  W112s[(2 * 3 + 1) * 5 + 3] = sq;
    W112s[(2 * 3 + 2) * 5 + 4] = sq;
    W112s[(0 * 3 + 0) * 5 + 4] = -sq;
  }
  __syncthreads();
  if (t == 0) { float ss = 0.f; for (int i = 0; i < 45; ++i)  ss += W112s[i] * W112s[i]; rn112 = rsqrtf(ss); }
  if (t == 1) { float ss = 0.f; for (int i = 0; i < 125; ++i) ss += W222s[i] * W222s[i]; rn222 = rsqrtf(ss); }
  __syncthreads();
  if (t < 45) W112s[t] *= rn112;
  else if (t < 170) W222s[t - 45] *= rn222;
  __syncthreads();

  if (t < 16) {
    float ssum = 0.f; for (int u = 0; u < 64; ++u) ssum += w_0e2e[u * 16 + t] * g0[u];
    a16[t] = ssum;
  } else if (t < 32) {
    int u = t - 16; float ssum = 0.f;
    for (int v = 0; v < 64; ++v) ssum += w_2e0e[u * 64 + v] * g0[v];
    c16[u] = ssum;
  } else if (t < 104) {
    int i2 = t - 32, u = i2 / 3, j = i2 % 3; float ssum = 0.f;
    for (int v = 0; v < 24; ++v) ssum += w_1o1o[u * 24 + v] * g1[v][j];
    T1[u][j] = ssum;
  } else if (t < 184) {
    int i2 = t - 104, u = i2 / 5, j = i2 % 5; float ssum = 0.f;
    for (int v = 0; v < 16; ++v) ssum += w_2e2e[u * 16 + v] * g2[v][j];
    T2[u][j] = ssum;
  }
  __syncthreads();
  if (t < 9) {
    int i = t / 3, j = t % 3; float ssum = 0.f;
    for (int u = 0; u < 24; ++u) ssum += g1[u][i] * T1[u][j];
    A1[i][j] = ssum;
  } else if (t < 34) {
    int i2 = t - 9, i = i2 / 5, j = i2 % 5; float ssum = 0.f;
    for (int u = 0; u < 16; ++u) ssum += g2[u][i] * T2[u][j];
    A2[i][j] = ssum;
  }
  __syncthreads();
  if (t < 5) {
    const float inv_s5 = 0.4472135954999579f;
    const float c = sqrtf(5.0f / 5248.0f);
    float s12 = 0.f;
    for (int v = 0; v < 16; ++v) s12 += (a16[v] + c16[v]) * g2[v][t];
    float s3 = 0.f;
    for (int i = 0; i < 3; ++i)
      for (int j = 0; j < 3; ++j) s3 += A1[i][j] * W112s[(i * 3 + j) * 5 + t];
    float s4 = 0.f;
    for (int i = 0; i < 5; ++i)
      for (int j = 0; j < 5; ++j) s4 += A2[i][j] * W222s[(i * 5 + j) * 5 + t];
    out[t] = c * (inv_s5 * s12 + s3 + s4);
  }
}

// ---- K1: canon check (from-half stream + folded to-half) + speculative edges ----
__global__ void __launch_bounds__(BLOCK)
spec_kernel(const float2* __restrict__ x, const float* __restrict__ pos,
            int N, int E,
            int* __restrict__ canon, float* __restrict__ partials) {
  const int b = blockIdx.x, t = threadIdx.x;
  const int lane = t & 63, wave = t >> 6;
  const int k0 = b * EPB;
  int k1 = k0 + EPB; if (k1 > E) k1 = E;

  int ok = 1;
  float s[18];
#pragma unroll
  for (int j = 0; j < 18; ++j) s[j] = 0.f;

  if (k0 < E) {
    // ---- from-half mask check: rows [k0,k1) of x, float4 (2 rows each) ----
    {
      const float4* x4 = (const float4*)x;
      const int nrows = k1 - k0;
      const int n4 = nrows >> 1;           // k0 even (EPB even)
      for (int q = t; q < n4; q += BLOCK) {
        float4 v = x4[(k0 >> 1) + q];
        ok &= (int)(v.x > 0.5f) & (int)!(v.y > 0.5f)
            & (int)(v.z > 0.5f) & (int)!(v.w > 0.5f);
      }
      if ((nrows & 1) && t == 0) {
        float2 v = x[k1 - 1];
        ok &= (int)(v.x > 0.5f) & (int)!(v.y > 0.5f);
      }
    }
    // ---- speculative edges + folded to-half mask check ----
    if ((E & 3) == 0) {
      int k = k0 + 4 * t;
      if (k + 4 <= k1) {
        const int g = k >> 2;
        const float4* pF4 = (const float4*)pos;
        const float4* pT4 = (const float4*)(pos + 3 * (size_t)E);
        const float4* xT4 = (const float4*)((const float*)x + 2 * (size_t)E);
        float4 fa = pF4[3 * g], fb = pF4[3 * g + 1], fc = pF4[3 * g + 2];
        float4 ta = pT4[3 * g], tb = pT4[3 * g + 1], tc = pT4[3 * g + 2];
        float4 xa = xT4[2 * g], xb = xT4[2 * g + 1];
        ok &= (int)!(xa.x > 0.5f) & (int)(xa.y > 0.5f)
            & (int)!(xa.z > 0.5f) & (int)(xa.w > 0.5f)
            & (int)!(xb.x > 0.5f) & (int)(xb.y > 0.5f)
            & (int)!(xb.z > 0.5f) & (int)(xb.w > 0.5f);
        accum18(s, xa.x, xa.y, ta.x - fa.x, ta.y - fa.y, ta.z - fa.z);
        accum18(s, xa.z, xa.w, ta.w - fa.w, tb.x - fb.x, tb.y - fb.y);
        accum18(s, xb.x, xb.y, tb.z - fb.z, tb.w - fb.w, tc.x - fc.x);
        accum18(s, xb.z, xb.w, tc.y - fc.y, tc.z - fc.z, tc.w - fc.w);
      } else {
        for (int kk = k; kk < k1; ++kk) {
          float2 nf = x[E + kk];
          ok &= (int)!(nf.x > 0.5f) & (int)(nf.y > 0.5f);
          accum18(s, nf.x, nf.y,
                  pos[3 * (size_t)(E + kk)]     - pos[3 * (size_t)kk],
                  pos[3 * (size_t)(E + kk) + 1] - pos[3 * (size_t)kk + 1],
                  pos[3 * (size_t)(E + kk) + 2] - pos[3 * (size_t)kk + 2]);
        }
      }
    } else {
      for (int k = k0 + t; k < k1; k += BLOCK) {
        float2 nf = x[E + k];
        ok &= (int)!(nf.x > 0.5f) & (int)(nf.y > 0.5f);
        accum18(s, nf.x, nf.y,
                pos[3 * (size_t)(E + k)]     - pos[3 * (size_t)k],
                pos[3 * (size_t)(E + k) + 1] - pos[3 * (size_t)k + 1],
                pos[3 * (size_t)(E + k) + 2] - pos[3 * (size_t)k + 2]);
      }
    }
  }

  ok = __all(ok) ? 1 : 0;
  __shared__ int okW[4];
  if (lane == 0) okW[wave] = ok;
  __syncthreads();
  if (t == 0) canon[b] = okW[0] & okW[1] & okW[2] & okW[3];

  block_reduce_store(s, partials + (size_t)b * 18);
}

// ---- K2 (1 block): AND flags; canonical -> reduce+finalize; else exact generic ----
__global__ void __launch_bounds__(BLOCK)
finalize_kernel(const float2* __restrict__ x, const float* __restrict__ pos,
                const int* __restrict__ canon, int nb, int N, int E,
                const float* __restrict__ partials,
                int* __restrict__ fromList, int* __restrict__ toList,
                const float* __restrict__ w0, const float* __restrict__ w1,
                const float* __restrict__ w2, const float* __restrict__ w_0e2e,
                const float* __restrict__ w_2e0e, const float* __restrict__ w_1o1o,
                const float* __restrict__ w_2e2e, float* __restrict__ out) {
  const int t = threadIdx.x;
  const int lane = t & 63, wave = t >> 6;
  __shared__ float accS[18];
  __shared__ int cr[4];

  int myok = 1;
  for (int k = t; k < nb; k += BLOCK) myok &= canon[k];
  myok = __all(myok) ? 1 : 0;
  if (lane == 0) cr[wave] = myok;
  __syncthreads();
  const int allCanon = cr[0] & cr[1] & cr[2] & cr[3];

  if (allCanon) {
    float s[18];
#pragma unroll
    for (int j = 0; j < 18; ++j) s[j] = 0.f;
    for (int p = t; p < nb; p += BLOCK) {
#pragma unroll
      for (int j = 0; j < 18; ++j) s[j] += partials[(size_t)p * 18 + j];
    }
    __syncthreads();
    block_reduce_store(s, accS);
    do_finalize(accS, w0, w1, w2, w_0e2e, w_2e0e, w_1o1o, w_2e2e, out);
    return;
  }

  // ---- generic exact path: this single block recomputes the nonzero lists ----
  __shared__ int wc[2][4][2];
  int cF = 0, cT = 0;
  const int iters = (N + BLOCK - 1) / BLOCK;
  for (int r = 0; r < iters; ++r) {
    const int i = r * BLOCK + t;
    bool mf = false, mt = false;
    if (i < N) { float2 v = x[i]; mf = v.x > 0.5f; mt = v.y > 0.5f; }
    unsigned long long bf = __ballot(mf);
    unsigned long long bt = __ballot(mt);
    const int p = r & 1;
    if (lane == 0) { wc[p][wave][0] = __popcll(bf); wc[p][wave][1] = __popcll(bt); }
    __syncthreads();
    int woF = 0, woT = 0, rtF = 0, rtT = 0;
    for (int w = 0; w < 4; ++w) {
      int a = wc[p][w][0], c = wc[p][w][1];
      if (w < wave) { woF += a; woT += c; }
      rtF += a; rtT += c;
    }
    unsigned long long lm = (1ull << lane) - 1ull;
    if (mf) { int rk = cF + woF + (int)__popcll(bf & lm); if (rk < E) fromList[rk] = i; }
    if (mt) { int rk = cT + woT + (int)__popcll(bt & lm); if (rk < E) toList[rk] = i; }
    cF += rtF; cT += rtT;
  }
  __syncthreads();
  int limF = cF < E ? cF : E;
  int limT = cT < E ? cT : E;

  float s[18];
#pragma unroll
  for (int j = 0; j < 18; ++j) s[j] = 0.f;
  for (int k = t; k < E; k += BLOCK) {
    int f  = (k < limF) ? fromList[k] : 0;   // nonzero pad fill_value = 0
    int tt = (k < limT) ? toList[k]   : 0;
    float2 nf = x[tt];
    accum18(s, nf.x, nf.y,
            pos[3 * (size_t)tt]     - pos[3 * (size_t)f],
            pos[3 * (size_t)tt + 1] - pos[3 * (size_t)f + 1],
            pos[3 * (size_t)tt + 2] - pos[3 * (size_t)f + 2]);
  }
  __syncthreads();
  block_reduce_store(s, accS);
  do_finalize(accS, w0, w1, w2, w_0e2e, w_2e0e, w_1o1o, w_2e2e, out);
}

extern "C" void kernel_launch(void* const* d_in, const int* in_sizes, int n_in,
                              void* d_out, int out_size, void* d_ws, size_t ws_size,
                              hipStream_t stream) {
  const float2* x      = (const float2*)d_in[0];
  const float*  pos    = (const float*)d_in[1];
  const float*  tp1_w0 = (const float*)d_in[2];
  const float*  tp1_w1 = (const float*)d_in[3];
  const float*  tp1_w2 = (const float*)d_in[4];
  const float*  w_0e2e = (const float*)d_in[5];
  const float*  w_2e0e = (const float*)d_in[6];
  const float*  w_1o1o = (const float*)d_in[7];
  const float*  w_2e2e = (const float*)d_in[8];
  float* outp = (float*)d_out;

  const int N = in_sizes[0] / 2;
  const int E = N / 2;
  int nb = (E + EPB - 1) / EPB;
  if (nb < 1) nb = 1;

  // ws layout: canon 4KB | partials (nb*18 f, <=72KB) | fromList E | toList E
  char* ws = (char*)d_ws;
  int*   canon    = (int*)ws;
  float* partials = (float*)(ws + 4096);
  int*   fromList = (int*)(ws + 4096 + 73728);
  int*   toList   = fromList + E;

  spec_kernel<<<nb, BLOCK, 0, stream>>>(x, pos, N, E, canon, partials);
  finalize_kernel<<<1, BLOCK, 0, stream>>>(x, pos, canon, nb, N, E, partials,
                                           fromList, toList,
                                           tp1_w0, tp1_w1, tp1_w2,
                                           w_0e2e, w_2e0e, w_1o1o, w_2e2e, outp);
}

// Round 12
// 22.417 us; speedup vs baseline: 2.1563x; 1.0818x over previous
//
#include <hip/hip_runtime.h>

#define SQ3F 1.7320508075688772f
#define SQ5F 2.2360679774997896f
#define BLOCK 256
#define EPB 2048        // edges (and from-rows) per K1 block: 8 edges/thread
#define PSTRIDE 20      // floats per partial row: 18 sums + flag + pad (80 B)

// m=2 basis matrices (exact transcription of _m2_basis; s = sqrt(3)/2)
__device__ const float M2B[5][3][3] = {
  {{0.f, 0.f, 0.8660254037844386f}, {0.f, 0.f, 0.f}, {0.8660254037844386f, 0.f, 0.f}},
  {{0.f, 0.8660254037844386f, 0.f}, {0.8660254037844386f, 0.f, 0.f}, {0.f, 0.f, 0.f}},
  {{-0.5f, 0.f, 0.f}, {0.f, 1.0f, 0.f}, {0.f, 0.f, -0.5f}},
  {{0.f, 0.f, 0.f}, {0.f, 0.f, 0.8660254037844386f}, {0.f, 0.8660254037844386f, 0.f}},
  {{-0.8660254037844386f, 0.f, 0.f}, {0.f, 0.f, 0.f}, {0.f, 0.f, 0.8660254037844386f}}
};

__device__ __forceinline__ void accum18(float* s, float nx, float ny,
                                        float ex, float ey, float ez) {
  float x2 = ex * ex, y2 = ey * ey, z2 = ez * ez;
  float s1x = SQ3F * ex, s1y = SQ3F * ey, s1z = SQ3F * ez;
  float s20 = SQ5F * SQ3F * ex * ez;
  float s21 = SQ5F * SQ3F * ex * ey;
  float s22 = SQ5F * (y2 - 0.5f * (x2 + z2));
  float s23 = SQ5F * SQ3F * ey * ez;
  float s24 = SQ5F * 0.5f * SQ3F * (z2 - x2);
  s[0] += nx;        s[1] += ny;
  s[2] += nx * s1x;  s[3] += nx * s1y;  s[4] += nx * s1z;
  s[5] += ny * s1x;  s[6] += ny * s1y;  s[7] += ny * s1z;
  s[8]  += nx * s20; s[9]  += nx * s21; s[10] += nx * s22;
  s[11] += nx * s23; s[12] += nx * s24;
  s[13] += ny * s20; s[14] += ny * s21; s[15] += ny * s22;
  s[16] += ny * s23; s[17] += ny * s24;
}

// block-wide reduce of 18 per-thread sums -> dst[0..18)
__device__ __forceinline__ void block_reduce_store(float* s, float* dst) {
  const int t = threadIdx.x, lane = t & 63, wave = t >> 6;
#pragma unroll
  for (int j = 0; j < 18; ++j)
    for (int o = 32; o; o >>= 1) s[j] += __shfl_down(s[j], o);
  __shared__ float ls[4][18];
  if (lane == 0) {
#pragma unroll
    for (int j = 0; j < 18; ++j) ls[wave][j] = s[j];
  }
  __syncthreads();
  if (t < 18) dst[t] = ls[0][t] + ls[1][t] + ls[2][t] + ls[3][t];
}

// full epilogue: accS (shared, 18 floats) -> out[5]; all 256 threads of one block
__device__ void do_finalize(const float* accS,
                            const float* w0, const float* w1, const float* w2,
                            const float* w_0e2e, const float* w_2e0e,
                            const float* w_1o1o, const float* w_2e2e,
                            float* out) {
  const int t = threadIdx.x;
  __shared__ float g0[64], g1[24][3], g2[16][5];
  __shared__ float a16[16], c16[16], T1[24][3], T2[16][5];
  __shared__ float A1[3][3], A2[5][5];
  __shared__ float W112s[45], W222s[125];
  __shared__ float rn112, rn222;
  if (t >= 64 && t < 109) W112s[t - 64] = 0.f;
  __syncthreads();   // accS + W112 zero visible

  const float inv = 0.28867513459481287f;  // 1/sqrt(12)
  if (t < 64) {
    g0[t] = inv * (accS[0] * w0[t] + accS[1] * w0[64 + t]);
  } else if (t < 136) {
    int i2 = t - 64, w = i2 / 3, j = i2 % 3;
    g1[w][j] = inv * (accS[2 + j] * w1[w] + accS[5 + j] * w1[24 + w]);
  } else if (t < 216) {
    int i2 = t - 136, w = i2 / 5, j = i2 % 5;
    g2[w][j] = inv * (accS[8 + j] * w2[w] + accS[13 + j] * w2[16 + w]);
  } else if (t < 241) {  // build W222 (25 threads)
    int idx = t - 216, i = idx / 5, j = idx % 5;
    float P[3][3];
    for (int a = 0; a < 3; ++a)
      for (int bb = 0; bb < 3; ++bb) {
        float sacc = 0.f;
        for (int cc = 0; cc < 3; ++cc)
          sacc += M2B[i][a][cc] * M2B[j][cc][bb] + M2B[j][a][cc] * M2B[i][cc][bb];
        P[a][bb] = 0.5f * sacc;
      }
    float tr3 = (P[0][0] + P[1][1] + P[2][2]) * (1.0f / 3.0f);
    P[0][0] -= tr3; P[1][1] -= tr3; P[2][2] -= tr3;
    for (int k = 0; k < 5; ++k) {
      float sacc = 0.f;
      for (int a = 0; a < 3; ++a)
        for (int bb = 0; bb < 3; ++bb) sacc += P[a][bb] * M2B[k][bb][a];
      W222s[(i * 5 + j) * 5 + k] = sacc * (1.0f / 1.5f);
    }
  }
  if (t == 0) {  // W112 nonzeros
    const float sq = 0.8660254037844386f;
    W112s[(0 * 3 + 2) * 5 + 0] = sq;  W112s[(2 * 3 + 0) * 5 + 0] = sq;
    W112s[(0 * 3 + 1) * 5 + 1] = sq;  W112s[(1 * 3 + 0) * 5 + 1] = sq;
    W112s[(1 * 3 + 1) * 5 + 2] = 1.0f;
    W112s[(0 * 3 + 0) * 5 + 2] = -0.5f;
    W112s[(2 * 3 + 2) * 5 + 2] = -0.5f;
    W112s[(1 * 3 + 2) * 5 + 3] = sq;  W112s[(2 * 3 + 1) * 5 + 3] = sq;
    W112s[(2 * 3 + 2) * 5 + 4] = sq;
    W112s[(0 * 3 + 0) * 5 + 4] = -sq;
  }
  __syncthreads();
  if (t == 0) { float ss = 0.f; for (int i = 0; i < 45; ++i)  ss += W112s[i] * W112s[i]; rn112 = rsqrtf(ss); }
  if (t == 1) { float ss = 0.f; for (int i = 0; i < 125; ++i) ss += W222s[i] * W222s[i]; rn222 = rsqrtf(ss); }
  __syncthreads();
  if (t < 45) W112s[t] *= rn112;
  else if (t < 170) W222s[t - 45] *= rn222;
  __syncthreads();

  if (t < 16) {
    float ssum = 0.f; for (int u = 0; u < 64; ++u) ssum += w_0e2e[u * 16 + t] * g0[u];
    a16[t] = ssum;
  } else if (t < 32) {
    int u = t - 16; float ssum = 0.f;
    for (int v = 0; v < 64; ++v) ssum += w_2e0e[u * 64 + v] * g0[v];
    c16[u] = ssum;
  } else if (t < 104) {
    int i2 = t - 32, u = i2 / 3, j = i2 % 3; float ssum = 0.f;
    for (int v = 0; v < 24; ++v) ssum += w_1o1o[u * 24 + v] * g1[v][j];
    T1[u][j] = ssum;
  } else if (t < 184) {
    int i2 = t - 104, u = i2 / 5, j = i2 % 5; float ssum = 0.f;
    for (int v = 0; v < 16; ++v) ssum += w_2e2e[u * 16 + v] * g2[v][j];
    T2[u][j] = ssum;
  }
  __syncthreads();
  if (t < 9) {
    int i = t / 3, j = t % 3; float ssum = 0.f;
    for (int u = 0; u < 24; ++u) ssum += g1[u][i] * T1[u][j];
    A1[i][j] = ssum;
  } else if (t < 34) {
    int i2 = t - 9, i = i2 / 5, j = i2 % 5; float ssum = 0.f;
    for (int u = 0; u < 16; ++u) ssum += g2[u][i] * T2[u][j];
    A2[i][j] = ssum;
  }
  __syncthreads();
  if (t < 5) {
    const float inv_s5 = 0.4472135954999579f;
    const float c = sqrtf(5.0f / 5248.0f);
    float s12 = 0.f;
    for (int v = 0; v < 16; ++v) s12 += (a16[v] + c16[v]) * g2[v][t];
    float s3 = 0.f;
    for (int i = 0; i < 3; ++i)
      for (int j = 0; j < 3; ++j) s3 += A1[i][j] * W112s[(i * 3 + j) * 5 + t];
    float s4 = 0.f;
    for (int i = 0; i < 5; ++i)
      for (int j = 0; j < 5; ++j) s4 += A2[i][j] * W222s[(i * 5 + j) * 5 + t];
    out[t] = c * (inv_s5 * s12 + s3 + s4);
  }
}

// ---- K1: canon check (from-half stream + folded to-half) + speculative edges ----
__global__ void __launch_bounds__(BLOCK)
spec_kernel(const float2* __restrict__ x, const float* __restrict__ pos,
            int N, int E, float* __restrict__ partials) {
  const int b = blockIdx.x, t = threadIdx.x;
  const int lane = t & 63, wave = t >> 6;
  const int k0 = b * EPB;
  int k1 = k0 + EPB; if (k1 > E) k1 = E;

  int ok = 1;
  float s[18];
#pragma unroll
  for (int j = 0; j < 18; ++j) s[j] = 0.f;

  if (k0 < E) {
    // ---- from-half mask check: rows [k0,k1) of x, float4 (2 rows each) ----
    {
      const float4* x4 = (const float4*)x;
      const int nrows = k1 - k0;
      const int n4 = nrows >> 1;           // k0 even (EPB even)
      for (int q = t; q < n4; q += BLOCK) {
        float4 v = x4[(k0 >> 1) + q];
        ok &= (int)(v.x > 0.5f) & (int)!(v.y > 0.5f)
            & (int)(v.z > 0.5f) & (int)!(v.w > 0.5f);
      }
      if ((nrows & 1) && t == 0) {
        float2 v = x[k1 - 1];
        ok &= (int)(v.x > 0.5f) & (int)!(v.y > 0.5f);
      }
    }
    // ---- speculative edges (quad per iter) + folded to-half mask check ----
    if ((E & 3) == 0) {
      for (int k = k0 + 4 * t; k < k1; k += 4 * BLOCK) {
        if (k + 4 <= k1) {
          const int g = k >> 2;
          const float4* pF4 = (const float4*)pos;
          const float4* pT4 = (const float4*)(pos + 3 * (size_t)E);
          const float4* xT4 = (const float4*)((const float*)x + 2 * (size_t)E);
          float4 fa = pF4[3 * g], fb = pF4[3 * g + 1], fc = pF4[3 * g + 2];
          float4 ta = pT4[3 * g], tb = pT4[3 * g + 1], tc = pT4[3 * g + 2];
          float4 xa = xT4[2 * g], xb = xT4[2 * g + 1];
          ok &= (int)!(xa.x > 0.5f) & (int)(xa.y > 0.5f)
              & (int)!(xa.z > 0.5f) & (int)(xa.w > 0.5f)
              & (int)!(xb.x > 0.5f) & (int)(xb.y > 0.5f)
              & (int)!(xb.z > 0.5f) & (int)(xb.w > 0.5f);
          accum18(s, xa.x, xa.y, ta.x - fa.x, ta.y - fa.y, ta.z - fa.z);
          accum18(s, xa.z, xa.w, ta.w - fa.w, tb.x - fb.x, tb.y - fb.y);
          accum18(s, xb.x, xb.y, tb.z - fb.z, tb.w - fb.w, tc.x - fc.x);
          accum18(s, xb.z, xb.w, tc.y - fc.y, tc.z - fc.z, tc.w - fc.w);
        } else {
          for (int kk = k; kk < k1; ++kk) {
            float2 nf = x[E + kk];
            ok &= (int)!(nf.x > 0.5f) & (int)(nf.y > 0.5f);
            accum18(s, nf.x, nf.y,
                    pos[3 * (size_t)(E + kk)]     - pos[3 * (size_t)kk],
                    pos[3 * (size_t)(E + kk) + 1] - pos[3 * (size_t)kk + 1],
                    pos[3 * (size_t)(E + kk) + 2] - pos[3 * (size_t)kk + 2]);
          }
        }
      }
    } else {
      for (int k = k0 + t; k < k1; k += BLOCK) {
        float2 nf = x[E + k];
        ok &= (int)!(nf.x > 0.5f) & (int)(nf.y > 0.5f);
        accum18(s, nf.x, nf.y,
                pos[3 * (size_t)(E + k)]     - pos[3 * (size_t)k],
                pos[3 * (size_t)(E + k) + 1] - pos[3 * (size_t)k + 1],
                pos[3 * (size_t)(E + k) + 2] - pos[3 * (size_t)k + 2]);
      }
    }
  }

  // canon flag -> shared (written before block_reduce_store's __syncthreads)
  __shared__ int okW[4];
  ok = __all(ok) ? 1 : 0;
  if (lane == 0) okW[wave] = ok;

  float* prow = partials + (size_t)b * PSTRIDE;
  block_reduce_store(s, prow);                 // internal __syncthreads covers okW
  if (t == 0) prow[18] = (okW[0] & okW[1] & okW[2] & okW[3]) ? 1.0f : 0.0f;
}

// ---- K2 (1 block): single pass over partial rows; canonical -> finalize; else generic ----
__global__ void __launch_bounds__(BLOCK)
finalize_kernel(const float2* __restrict__ x, const float* __restrict__ pos,
                int nb, int N, int E,
                const float* __restrict__ partials,
                int* __restrict__ fromList, int* __restrict__ toList,
                const float* __restrict__ w0, const float* __restrict__ w1,
                const float* __restrict__ w2, const float* __restrict__ w_0e2e,
                const float* __restrict__ w_2e0e, const float* __restrict__ w_1o1o,
                const float* __restrict__ w_2e2e, float* __restrict__ out) {
  const int t = threadIdx.x;
  const int lane = t & 63, wave = t >> 6;
  __shared__ float accS[18];
  __shared__ int cr[4];

  // one pass: sum 18 stats and AND the flag
  float s[18];
#pragma unroll
  for (int j = 0; j < 18; ++j) s[j] = 0.f;
  int myok = 1;
  for (int p = t; p < nb; p += BLOCK) {
    const float* row = partials + (size_t)p * PSTRIDE;
#pragma unroll
    for (int j = 0; j < 18; ++j) s[j] += row[j];
    myok &= (row[18] == 1.0f);
  }
  myok = __all(myok) ? 1 : 0;
  if (lane == 0) cr[wave] = myok;
  block_reduce_store(s, accS);                 // internal sync covers cr
  const int allCanon = cr[0] & cr[1] & cr[2] & cr[3];

  if (allCanon) {
    do_finalize(accS, w0, w1, w2, w_0e2e, w_2e0e, w_1o1o, w_2e2e, out);
    return;
  }

  // ---- generic exact path: recompute the nonzero lists from x ----
  __syncthreads();
  __shared__ int wc[2][4][2];
  int cF = 0, cT = 0;
  const int iters = (N + BLOCK - 1) / BLOCK;
  for (int r = 0; r < iters; ++r) {
    const int i = r * BLOCK + t;
    bool mf = false, mt = false;
    if (i < N) { float2 v = x[i]; mf = v.x > 0.5f; mt = v.y > 0.5f; }
    unsigned long long bf = __ballot(mf);
    unsigned long long bt = __ballot(mt);
    const int p = r & 1;
    if (lane == 0) { wc[p][wave][0] = __popcll(bf); wc[p][wave][1] = __popcll(bt); }
    __syncthreads();
    int woF = 0, woT = 0, rtF = 0, rtT = 0;
    for (int w = 0; w < 4; ++w) {
      int a = wc[p][w][0], c = wc[p][w][1];
      if (w < wave) { woF += a; woT += c; }
      rtF += a; rtT += c;
    }
    unsigned long long lm = (1ull << lane) - 1ull;
    if (mf) { int rk = cF + woF + (int)__popcll(bf & lm); if (rk < E) fromList[rk] = i; }
    if (mt) { int rk = cT + woT + (int)__popcll(bt & lm); if (rk < E) toList[rk] = i; }
    cF += rtF; cT += rtT;
  }
  __syncthreads();
  int limF = cF < E ? cF : E;
  int limT = cT < E ? cT : E;

  float s2[18];
#pragma unroll
  for (int j = 0; j < 18; ++j) s2[j] = 0.f;
  for (int k = t; k < E; k += BLOCK) {
    int f  = (k < limF) ? fromList[k] : 0;   // nonzero pad fill_value = 0
    int tt = (k < limT) ? toList[k]   : 0;
    float2 nf = x[tt];
    accum18(s2, nf.x, nf.y,
            pos[3 * (size_t)tt]     - pos[3 * (size_t)f],
            pos[3 * (size_t)tt + 1] - pos[3 * (size_t)f + 1],
            pos[3 * (size_t)tt + 2] - pos[3 * (size_t)f + 2]);
  }
  __syncthreads();
  block_reduce_store(s2, accS);
  do_finalize(accS, w0, w1, w2, w_0e2e, w_2e0e, w_1o1o, w_2e2e, out);
}

extern "C" void kernel_launch(void* const* d_in, const int* in_sizes, int n_in,
                              void* d_out, int out_size, void* d_ws, size_t ws_size,
                              hipStream_t stream) {
  const float2* x      = (const float2*)d_in[0];
  const float*  pos    = (const float*)d_in[1];
  const float*  tp1_w0 = (const float*)d_in[2];
  const float*  tp1_w1 = (const float*)d_in[3];
  const float*  tp1_w2 = (const float*)d_in[4];
  const float*  w_0e2e = (const float*)d_in[5];
  const float*  w_2e0e = (const float*)d_in[6];
  const float*  w_1o1o = (const float*)d_in[7];
  const float*  w_2e2e = (const float*)d_in[8];
  float* outp = (float*)d_out;

  const int N = in_sizes[0] / 2;
  const int E = N / 2;
  int nb = (E + EPB - 1) / EPB;
  if (nb < 1) nb = 1;

  // ws layout: partials (nb*PSTRIDE floats, <=80KB) | fromList E | toList E
  char* ws = (char*)d_ws;
  float* partials = (float*)ws;
  int*   fromList = (int*)(ws + 81920);
  int*   toList   = fromList + E;

  spec_kernel<<<nb, BLOCK, 0, stream>>>(x, pos, N, E, partials);
  finalize_kernel<<<1, BLOCK, 0, stream>>>(x, pos, nb, N, E, partials,
                                           fromList, toList,
                                           tp1_w0, tp1_w1, tp1_w2,
                                           w_0e2e, w_2e0e, w_1o1o, w_2e2e, outp);
}

// Round 13
// 21.857 us; speedup vs baseline: 2.2115x; 1.0256x over previous
//
#include <hip/hip_runtime.h>

#define SQ3F 1.7320508075688772f
#define SQ5F 2.2360679774997896f
#define BLOCK 256
#define EPB 2048        // edges (and from-rows) per K1 block: 8 edges/thread
#define PSTRIDE 20      // floats per partial row: 18 sums + flag + pad (80 B)

// m=2 basis matrices (exact transcription of _m2_basis; s = sqrt(3)/2)
__device__ const float M2B[5][3][3] = {
  {{0.f, 0.f, 0.8660254037844386f}, {0.f, 0.f, 0.f}, {0.8660254037844386f, 0.f, 0.f}},
  {{0.f, 0.8660254037844386f, 0.f}, {0.8660254037844386f, 0.f, 0.f}, {0.f, 0.f, 0.f}},
  {{-0.5f, 0.f, 0.f}, {0.f, 1.0f, 0.f}, {0.f, 0.f, -0.5f}},
  {{0.f, 0.f, 0.f}, {0.f, 0.f, 0.8660254037844386f}, {0.f, 0.8660254037844386f, 0.f}},
  {{-0.8660254037844386f, 0.f, 0.f}, {0.f, 0.f, 0.f}, {0.f, 0.f, 0.8660254037844386f}}
};

__device__ __forceinline__ void accum18(float* s, float nx, float ny,
                                        float ex, float ey, float ez) {
  float x2 = ex * ex, y2 = ey * ey, z2 = ez * ez;
  float s1x = SQ3F * ex, s1y = SQ3F * ey, s1z = SQ3F * ez;
  float s20 = SQ5F * SQ3F * ex * ez;
  float s21 = SQ5F * SQ3F * ex * ey;
  float s22 = SQ5F * (y2 - 0.5f * (x2 + z2));
  float s23 = SQ5F * SQ3F * ey * ez;
  float s24 = SQ5F * 0.5f * SQ3F * (z2 - x2);
  s[0] += nx;        s[1] += ny;
  s[2] += nx * s1x;  s[3] += nx * s1y;  s[4] += nx * s1z;
  s[5] += ny * s1x;  s[6] += ny * s1y;  s[7] += ny * s1z;
  s[8]  += nx * s20; s[9]  += nx * s21; s[10] += nx * s22;
  s[11] += nx * s23; s[12] += nx * s24;
  s[13] += ny * s20; s[14] += ny * s21; s[15] += ny * s22;
  s[16] += ny * s23; s[17] += ny * s24;
}

// block-wide reduce of 18 per-thread sums -> dst[0..18)
__device__ __forceinline__ void block_reduce_store(float* s, float* dst) {
  const int t = threadIdx.x, lane = t & 63, wave = t >> 6;
#pragma unroll
  for (int j = 0; j < 18; ++j)
    for (int o = 32; o; o >>= 1) s[j] += __shfl_down(s[j], o);
  __shared__ float ls[4][18];
  if (lane == 0) {
#pragma unroll
    for (int j = 0; j < 18; ++j) ls[wave][j] = s[j];
  }
  __syncthreads();
  if (t < 18) dst[t] = ls[0][t] + ls[1][t] + ls[2][t] + ls[3][t];
}

// full epilogue: accS (shared, 18 floats) -> out[5]; all 256 threads of one block
__device__ void do_finalize(const float* accS,
                            const float* w0, const float* w1, const float* w2,
                            const float* w_0e2e, const float* w_2e0e,
                            const float* w_1o1o, const float* w_2e2e,
                            float* out) {
  const int t = threadIdx.x;
  __shared__ float g0[64], g1[24][3], g2[16][5];
  __shared__ float a16[16], c16[16], T1[24][3], T2[16][5];
  __shared__ float A1[3][3], A2[5][5];
  __shared__ float W112s[45], W222s[125];
  __shared__ float rn112, rn222;
  if (t >= 64 && t < 109) W112s[t - 64] = 0.f;
  __syncthreads();   // accS + W112 zero visible

  const float inv = 0.28867513459481287f;  // 1/sqrt(12)
  if (t < 64) {
    g0[t] = inv * (accS[0] * w0[t] + accS[1] * w0[64 + t]);
  } else if (t < 136) {
    int i2 = t - 64, w = i2 / 3, j = i2 % 3;
    g1[w][j] = inv * (accS[2 + j] * w1[w] + accS[5 + j] * w1[24 + w]);
  } else if (t < 216) {
    int i2 = t - 136, w = i2 / 5, j = i2 % 5;
    g2[w][j] = inv * (accS[8 + j] * w2[w] + accS[13 + j] * w2[16 + w]);
  } else if (t < 241) {  // build W222 (25 threads)
    int idx = t - 216, i = idx / 5, j = idx % 5;
    float P[3][3];
    for (int a = 0; a < 3; ++a)
      for (int bb = 0; bb < 3; ++bb) {
        float sacc = 0.f;
        for (int cc = 0; cc < 3; ++cc)
          sacc += M2B[i][a][cc] * M2B[j][cc][bb] + M2B[j][a][cc] * M2B[i][cc][bb];
        P[a][bb] = 0.5f * sacc;
      }
    float tr3 = (P[0][0] + P[1][1] + P[2][2]) * (1.0f / 3.0f);
    P[0][0] -= tr3; P[1][1] -= tr3; P[2][2] -= tr3;
    for (int k = 0; k < 5; ++k) {
      float sacc = 0.f;
      for (int a = 0; a < 3; ++a)
        for (int bb = 0; bb < 3; ++bb) sacc += P[a][bb] * M2B[k][bb][a];
      W222s[(i * 5 + j) * 5 + k] = sacc * (1.0f / 1.5f);
    }
  }
  if (t == 0) {  // W112 nonzeros
    const float sq = 0.8660254037844386f;
    W112s[(0 * 3 + 2) * 5 + 0] = sq;  W112s[(2 * 3 + 0) * 5 + 0] = sq;
    W112s[(0 * 3 + 1) * 5 + 1] = sq;  W112s[(1 * 3 + 0) * 5 + 1] = sq;
    W112s[(1 * 3 + 1) * 5 + 2] = 1.0f;
    W112s[(0 * 3 + 0) * 5 + 2] = -0.5f;
    W112s[(2 * 3 + 2) * 5 + 2] = -0.5f;
    W112s[(1 * 3 + 2) * 5 + 3] = sq;  W112s[(2 * 3 + 1) * 5 + 3] = sq;
    W112s[(2 * 3 + 2) * 5 + 4] = sq;
    W112s[(0 * 3 + 0) * 5 + 4] = -sq;
  }
  __syncthreads();
  if (t == 0) { float ss = 0.f; for (int i = 0; i < 45; ++i)  ss += W112s[i] * W112s[i]; rn112 = rsqrtf(ss); }
  if (t == 1) { float ss = 0.f; for (int i = 0; i < 125; ++i) ss += W222s[i] * W222s[i]; rn222 = rsqrtf(ss); }
  __syncthreads();
  if (t < 45) W112s[t] *= rn112;
  else if (t < 170) W222s[t - 45] *= rn222;
  __syncthreads();

  if (t < 16) {
    float ssum = 0.f; for (int u = 0; u < 64; ++u) ssum += w_0e2e[u * 16 + t] * g0[u];
    a16[t] = ssum;
  } else if (t < 32) {
    int u = t - 16; float ssum = 0.f;
    for (int v = 0; v < 64; ++v) ssum += w_2e0e[u * 64 + v] * g0[v];
    c16[u] = ssum;
  } else if (t < 104) {
    int i2 = t - 32, u = i2 / 3, j = i2 % 3; float ssum = 0.f;
    for (int v = 0; v < 24; ++v) ssum += w_1o1o[u * 24 + v] * g1[v][j];
    T1[u][j] = ssum;
  } else if (t < 184) {
    int i2 = t - 104, u = i2 / 5, j = i2 % 5; float ssum = 0.f;
    for (int v = 0; v < 16; ++v) ssum += w_2e2e[u * 16 + v] * g2[v][j];
    T2[u][j] = ssum;
  }
  __syncthreads();
  if (t < 9) {
    int i = t / 3, j = t % 3; float ssum = 0.f;
    for (int u = 0; u < 24; ++u) ssum += g1[u][i] * T1[u][j];
    A1[i][j] = ssum;
  } else if (t < 34) {
    int i2 = t - 9, i = i2 / 5, j = i2 % 5; float ssum = 0.f;
    for (int u = 0; u < 16; ++u) ssum += g2[u][i] * T2[u][j];
    A2[i][j] = ssum;
  }
  __syncthreads();
  if (t < 5) {
    const float inv_s5 = 0.4472135954999579f;
    const float c = sqrtf(5.0f / 5248.0f);
    float s12 = 0.f;
    for (int v = 0; v < 16; ++v) s12 += (a16[v] + c16[v]) * g2[v][t];
    float s3 = 0.f;
    for (int i = 0; i < 3; ++i)
      for (int j = 0; j < 3; ++j) s3 += A1[i][j] * W112s[(i * 3 + j) * 5 + t];
    float s4 = 0.f;
    for (int i = 0; i < 5; ++i)
      for (int j = 0; j < 5; ++j) s4 += A2[i][j] * W222s[(i * 5 + j) * 5 + t];
    out[t] = c * (inv_s5 * s12 + s3 + s4);
  }
}

// ---- K1: fused canon check + speculative edges (single loop, 10 loads/iter) ----
__global__ void __launch_bounds__(BLOCK)
spec_kernel(const float2* __restrict__ x, const float* __restrict__ pos,
            int N, int E, float* __restrict__ partials) {
  const int b = blockIdx.x, t = threadIdx.x;
  const int lane = t & 63, wave = t >> 6;
  const int k0 = b * EPB;
  int k1 = k0 + EPB; if (k1 > E) k1 = E;

  int ok = 1;
  float s[18];
#pragma unroll
  for (int j = 0; j < 18; ++j) s[j] = 0.f;

  if (k0 < E) {
    if ((E & 3) == 0 && ((k1 - k0) & 3) == 0) {
      // fused quad loop: rows k..k+3 (from-half) + edges k..k+3 per iteration
      const float4* xF4 = (const float4*)x;                       // 2 rows each
      const float4* pF4 = (const float4*)pos;
      const float4* pT4 = (const float4*)(pos + 3 * (size_t)E);
      const float4* xT4 = (const float4*)((const float*)x + 2 * (size_t)E);
      for (int k = k0 + 4 * t; k < k1; k += 4 * BLOCK) {
        const int g = k >> 2;
        float4 va = xF4[(k >> 1)], vb = xF4[(k >> 1) + 1];        // from-rows k..k+3
        float4 fa = pF4[3 * g], fb = pF4[3 * g + 1], fc = pF4[3 * g + 2];
        float4 ta = pT4[3 * g], tb = pT4[3 * g + 1], tc = pT4[3 * g + 2];
        float4 xa = xT4[2 * g], xb = xT4[2 * g + 1];              // to-rows E+k..E+k+3
        ok &= (int)(va.x > 0.5f) & (int)!(va.y > 0.5f)
            & (int)(va.z > 0.5f) & (int)!(va.w > 0.5f)
            & (int)(vb.x > 0.5f) & (int)!(vb.y > 0.5f)
            & (int)(vb.z > 0.5f) & (int)!(vb.w > 0.5f)
            & (int)!(xa.x > 0.5f) & (int)(xa.y > 0.5f)
            & (int)!(xa.z > 0.5f) & (int)(xa.w > 0.5f)
            & (int)!(xb.x > 0.5f) & (int)(xb.y > 0.5f)
            & (int)!(xb.z > 0.5f) & (int)(xb.w > 0.5f);
        accum18(s, xa.x, xa.y, ta.x - fa.x, ta.y - fa.y, ta.z - fa.z);
        accum18(s, xa.z, xa.w, ta.w - fa.w, tb.x - fb.x, tb.y - fb.y);
        accum18(s, xb.x, xb.y, tb.z - fb.z, tb.w - fb.w, tc.x - fc.x);
        accum18(s, xb.z, xb.w, tc.y - fc.y, tc.z - fc.z, tc.w - fc.w);
      }
    } else {
      // generic-alignment scalar loop (same semantics)
      for (int k = k0 + t; k < k1; k += BLOCK) {
        float2 vf = x[k];
        ok &= (int)(vf.x > 0.5f) & (int)!(vf.y > 0.5f);
        float2 nf = x[E + k];
        ok &= (int)!(nf.x > 0.5f) & (int)(nf.y > 0.5f);
        accum18(s, nf.x, nf.y,
                pos[3 * (size_t)(E + k)]     - pos[3 * (size_t)k],
                pos[3 * (size_t)(E + k) + 1] - pos[3 * (size_t)k + 1],
                pos[3 * (size_t)(E + k) + 2] - pos[3 * (size_t)k + 2]);
      }
    }
  }

  // canon flag -> shared (written before block_reduce_store's __syncthreads)
  __shared__ int okW[4];
  ok = __all(ok) ? 1 : 0;
  if (lane == 0) okW[wave] = ok;

  float* prow = partials + (size_t)b * PSTRIDE;
  block_reduce_store(s, prow);                 // internal __syncthreads covers okW
  if (t == 0) prow[18] = (okW[0] & okW[1] & okW[2] & okW[3]) ? 1.0f : 0.0f;
}

// ---- K2 (1 block): vectorized pass over partial rows; canonical -> finalize; else generic ----
__global__ void __launch_bounds__(BLOCK)
finalize_kernel(const float2* __restrict__ x, const float* __restrict__ pos,
                int nb, int N, int E,
                const float* __restrict__ partials,
                int* __restrict__ fromList, int* __restrict__ toList,
                const float* __restrict__ w0, const float* __restrict__ w1,
                const float* __restrict__ w2, const float* __restrict__ w_0e2e,
                const float* __restrict__ w_2e0e, const float* __restrict__ w_1o1o,
                const float* __restrict__ w_2e2e, float* __restrict__ out) {
  const int t = threadIdx.x;
  const int lane = t & 63, wave = t >> 6;
  __shared__ float accS[18];
  __shared__ int cr[4];

  // one vectorized pass: sum 18 stats and AND the flag (rows are 80 B = 5 float4)
  float s[18];
#pragma unroll
  for (int j = 0; j < 18; ++j) s[j] = 0.f;
  int myok = 1;
  for (int p = t; p < nb; p += BLOCK) {
    const float4* row = (const float4*)(partials + (size_t)p * PSTRIDE);
    float4 f0 = row[0], f1 = row[1], f2 = row[2], f3 = row[3], f4 = row[4];
    s[0] += f0.x;  s[1] += f0.y;  s[2] += f0.z;  s[3] += f0.w;
    s[4] += f1.x;  s[5] += f1.y;  s[6] += f1.z;  s[7] += f1.w;
    s[8] += f2.x;  s[9] += f2.y;  s[10] += f2.z; s[11] += f2.w;
    s[12] += f3.x; s[13] += f3.y; s[14] += f3.z; s[15] += f3.w;
    s[16] += f4.x; s[17] += f4.y;
    myok &= (f4.z == 1.0f);
  }
  myok = __all(myok) ? 1 : 0;
  if (lane == 0) cr[wave] = myok;
  block_reduce_store(s, accS);                 // internal sync covers cr
  const int allCanon = cr[0] & cr[1] & cr[2] & cr[3];

  if (allCanon) {
    do_finalize(accS, w0, w1, w2, w_0e2e, w_2e0e, w_1o1o, w_2e2e, out);
    return;
  }

  // ---- generic exact path: recompute the nonzero lists from x ----
  __syncthreads();
  __shared__ int wc[2][4][2];
  int cF = 0, cT = 0;
  const int iters = (N + BLOCK - 1) / BLOCK;
  for (int r = 0; r < iters; ++r) {
    const int i = r * BLOCK + t;
    bool mf = false, mt = false;
    if (i < N) { float2 v = x[i]; mf = v.x > 0.5f; mt = v.y > 0.5f; }
    unsigned long long bf = __ballot(mf);
    unsigned long long bt = __ballot(mt);
    const int p = r & 1;
    if (lane == 0) { wc[p][wave][0] = __popcll(bf); wc[p][wave][1] = __popcll(bt); }
    __syncthreads();
    int woF = 0, woT = 0, rtF = 0, rtT = 0;
    for (int w = 0; w < 4; ++w) {
      int a = wc[p][w][0], c = wc[p][w][1];
      if (w < wave) { woF += a; woT += c; }
      rtF += a; rtT += c;
    }
    unsigned long long lm = (1ull << lane) - 1ull;
    if (mf) { int rk = cF + woF + (int)__popcll(bf & lm); if (rk < E) fromList[rk] = i; }
    if (mt) { int rk = cT + woT + (int)__popcll(bt & lm); if (rk < E) toList[rk] = i; }
    cF += rtF; cT += rtT;
  }
  __syncthreads();
  int limF = cF < E ? cF : E;
  int limT = cT < E ? cT : E;

  float s2[18];
#pragma unroll
  for (int j = 0; j < 18; ++j) s2[j] = 0.f;
  for (int k = t; k < E; k += BLOCK) {
    int f  = (k < limF) ? fromList[k] : 0;   // nonzero pad fill_value = 0
    int tt = (k < limT) ? toList[k]   : 0;
    float2 nf = x[tt];
    accum18(s2, nf.x, nf.y,
            pos[3 * (size_t)tt]     - pos[3 * (size_t)f],
            pos[3 * (size_t)tt + 1] - pos[3 * (size_t)f + 1],
            pos[3 * (size_t)tt + 2] - pos[3 * (size_t)f + 2]);
  }
  __syncthreads();
  block_reduce_store(s2, accS);
  do_finalize(accS, w0, w1, w2, w_0e2e, w_2e0e, w_1o1o, w_2e2e, out);
}

extern "C" void kernel_launch(void* const* d_in, const int* in_sizes, int n_in,
                              void* d_out, int out_size, void* d_ws, size_t ws_size,
                              hipStream_t stream) {
  const float2* x      = (const float2*)d_in[0];
  const float*  pos    = (const float*)d_in[1];
  const float*  tp1_w0 = (const float*)d_in[2];
  const float*  tp1_w1 = (const float*)d_in[3];
  const float*  tp1_w2 = (const float*)d_in[4];
  const float*  w_0e2e = (const float*)d_in[5];
  const float*  w_2e0e = (const float*)d_in[6];
  const float*  w_1o1o = (const float*)d_in[7];
  const float*  w_2e2e = (const float*)d_in[8];
  float* outp = (float*)d_out;

  const int N = in_sizes[0] / 2;
  const int E = N / 2;
  int nb = (E + EPB - 1) / EPB;
  if (nb < 1) nb = 1;

  // ws layout: partials (nb*PSTRIDE floats, <=80KB) | fromList E | toList E
  char* ws = (char*)d_ws;
  float* partials = (float*)ws;
  int*   fromList = (int*)(ws + 81920);
  int*   toList   = fromList + E;

  spec_kernel<<<nb, BLOCK, 0, stream>>>(x, pos, N, E, partials);
  finalize_kernel<<<1, BLOCK, 0, stream>>>(x, pos, nb, N, E, partials,
                                           fromList, toList,
                                           tp1_w0, tp1_w1, tp1_w2,
                                           w_0e2e, w_2e0e, w_1o1o, w_2e2e, outp);
}